// Round 1
// baseline (1139.279 us; speedup 1.0000x reference)
//
#include <hip/hip_runtime.h>
#include <math.h>

#define NN   50000
#define EE   800000
#define HH   4
#define CC   32
#define DINN 128
#define ED   16
#define NEGS 0.2f
#define LNEPS 1e-5f

// ---------------------------------------------------------------------------
// K1: v_edge[d][h] = sum_c W_edge[d][h*32+c] * att_edge[h][c]   (16 x 4)
// ---------------------------------------------------------------------------
__global__ void k_precompute(const float* __restrict__ W_edge,
                             const float* __restrict__ att_edge,
                             float* __restrict__ v_edge) {
    int t = threadIdx.x;
    if (t < ED * HH) {
        int d = t >> 2, h = t & 3;
        float s = 0.f;
        for (int c = 0; c < CC; ++c)
            s += W_edge[d * (HH * CC) + h * CC + c] * att_edge[h * CC + c];
        v_edge[t] = s;
    }
}

// ---------------------------------------------------------------------------
// K2: h = x @ W_lin  (N x 128), plus a_src[n][h], a_dst[n][h]
// 64 rows / block, W_lin staged in LDS (64KB), float4 LDS reads.
// thread t: row_local = t>>5 (8 rows/step), cols j0..j0+3 with j0=(t&31)*4
// ---------------------------------------------------------------------------
__global__ __launch_bounds__(256, 2) void k_node(
        const float* __restrict__ x, const float* __restrict__ W_lin,
        const float* __restrict__ att_src, const float* __restrict__ att_dst,
        float* __restrict__ hbuf, float* __restrict__ a_src, float* __restrict__ a_dst) {
    __shared__ float Wl[DINN * DINN];   // 64 KB
    __shared__ float xr[8 * DINN];      // 4 KB
    int t = threadIdx.x;
    for (int i = t; i < DINN * DINN; i += 256) Wl[i] = W_lin[i];

    int row0 = blockIdx.x * 64;
    int rl   = t >> 5;            // 0..7
    int j0   = (t & 31) * 4;      // 0..124
    int head = (t & 31) >> 3;     // 0..3
    int c0   = (t & 7) * 4;       // 0..28
    float4 as4 = *(const float4*)&att_src[head * CC + c0];
    float4 ad4 = *(const float4*)&att_dst[head * CC + c0];

    for (int rb = 0; rb < 64; rb += 8) {
        __syncthreads();
        // stage 8 rows of x (1024 floats = 256 float4)
        long gidx = (long)(row0 + rb) * DINN + t * 4;
        float4 xv4 = make_float4(0.f, 0.f, 0.f, 0.f);
        if (gidx < (long)NN * DINN) xv4 = *(const float4*)&x[gidx];
        ((float4*)xr)[t] = xv4;
        __syncthreads();

        int row = row0 + rb + rl;
        float ax = 0.f, ay = 0.f, az = 0.f, aw = 0.f;
        #pragma unroll 16
        for (int d = 0; d < DINN; ++d) {
            float xv = xr[rl * DINN + d];
            float4 w = *(const float4*)&Wl[d * DINN + j0];
            ax = fmaf(xv, w.x, ax);
            ay = fmaf(xv, w.y, ay);
            az = fmaf(xv, w.z, az);
            aw = fmaf(xv, w.w, aw);
        }
        if (row < NN) {
            *(float4*)&hbuf[(long)row * DINN + j0] = make_float4(ax, ay, az, aw);
        }
        float ps = ax * as4.x + ay * as4.y + az * as4.z + aw * as4.w;
        float pd = ax * ad4.x + ay * ad4.y + az * ad4.z + aw * ad4.w;
        #pragma unroll
        for (int mask = 1; mask < 8; mask <<= 1) {
            ps += __shfl_xor(ps, mask);
            pd += __shfl_xor(pd, mask);
        }
        if ((t & 7) == 0 && row < NN) {
            a_src[row * 4 + head] = ps;
            a_dst[row * 4 + head] = pd;
        }
    }
}

// ---------------------------------------------------------------------------
// K3: per edge: ea = relu(edge_attr @ W_ep + b_ep);
//     atomic loop_sum[dst] += ea ; cnt[dst]++
// ---------------------------------------------------------------------------
__global__ __launch_bounds__(256) void k_edge1(
        const int* __restrict__ ei, const float* __restrict__ edge_attr,
        const float* __restrict__ W_ep, const float* __restrict__ b_ep,
        float* __restrict__ loop_sum, int* __restrict__ cnt) {
    __shared__ float Wl[ED * ED];
    __shared__ float bl[ED];
    int t = threadIdx.x;
    if (t < ED * ED) Wl[t] = W_ep[t];
    if (t < ED) bl[t] = b_ep[t];
    __syncthreads();

    int e = blockIdx.x * 256 + t;
    if (e >= EE) return;

    float a[ED];
    const float4* ap = (const float4*)(edge_attr + (long)e * ED);
    float4 a0 = ap[0], a1 = ap[1], a2 = ap[2], a3 = ap[3];
    a[0]=a0.x; a[1]=a0.y; a[2]=a0.z; a[3]=a0.w;
    a[4]=a1.x; a[5]=a1.y; a[6]=a1.z; a[7]=a1.w;
    a[8]=a2.x; a[9]=a2.y; a[10]=a2.z; a[11]=a2.w;
    a[12]=a3.x; a[13]=a3.y; a[14]=a3.z; a[15]=a3.w;

    float r[ED];
    #pragma unroll
    for (int j = 0; j < ED; ++j) r[j] = bl[j];
    #pragma unroll
    for (int d = 0; d < ED; ++d) {
        float av = a[d];
        #pragma unroll
        for (int j = 0; j < ED; ++j) r[j] = fmaf(av, Wl[d * ED + j], r[j]);
    }

    int dst = ei[EE + e];
    float* ls = loop_sum + (long)dst * ED;
    #pragma unroll
    for (int j = 0; j < ED; ++j) atomicAdd(ls + j, fmaxf(r[j], 0.f));
    atomicAdd(cnt + dst, 1);
}

// ---------------------------------------------------------------------------
// K4: exclusive scan of cnt[NN] -> row_start, off (single block, 1024 thr)
// ---------------------------------------------------------------------------
__global__ __launch_bounds__(1024) void k_scan(const int* __restrict__ cnt,
                                               int* __restrict__ row_start,
                                               int* __restrict__ off) {
    __shared__ int s[1024];
    int t = threadIdx.x;
    const int CH = (NN + 1023) / 1024;
    int i0 = t * CH;
    int i1 = i0 + CH; if (i1 > NN) i1 = NN; if (i0 > NN) i0 = NN;
    int loc = 0;
    for (int i = i0; i < i1; ++i) loc += cnt[i];
    s[t] = loc;
    __syncthreads();
    for (int d2 = 1; d2 < 1024; d2 <<= 1) {
        int v = (t >= d2) ? s[t - d2] : 0;
        __syncthreads();
        s[t] += v;
        __syncthreads();
    }
    int run = s[t] - loc;  // exclusive
    for (int i = i0; i < i1; ++i) {
        row_start[i] = run;
        off[i] = run;
        run += cnt[i];
    }
    if (t == 1023) row_start[NN] = run;
}

// ---------------------------------------------------------------------------
// K5: per edge: recompute ea, alpha[h] = leaky(a_src[src]+a_dst[dst]+ea.v_edge)
//     scatter into CSR slot via atomic cursor.
// ---------------------------------------------------------------------------
__global__ __launch_bounds__(256) void k_edge2(
        const int* __restrict__ ei, const float* __restrict__ edge_attr,
        const float* __restrict__ W_ep, const float* __restrict__ b_ep,
        const float* __restrict__ v_edge,
        const float* __restrict__ a_src, const float* __restrict__ a_dst,
        int* __restrict__ off, int* __restrict__ csr_src,
        float4* __restrict__ csr_alpha) {
    __shared__ float Wl[ED * ED];
    __shared__ float bl[ED];
    __shared__ float vl[ED * 4];
    int t = threadIdx.x;
    if (t < ED * ED) Wl[t] = W_ep[t];
    if (t < ED) bl[t] = b_ep[t];
    if (t < ED * 4) vl[t] = v_edge[t];
    __syncthreads();

    int e = blockIdx.x * 256 + t;
    if (e >= EE) return;

    float a[ED];
    const float4* ap = (const float4*)(edge_attr + (long)e * ED);
    float4 a0 = ap[0], a1 = ap[1], a2 = ap[2], a3 = ap[3];
    a[0]=a0.x; a[1]=a0.y; a[2]=a0.z; a[3]=a0.w;
    a[4]=a1.x; a[5]=a1.y; a[6]=a1.z; a[7]=a1.w;
    a[8]=a2.x; a[9]=a2.y; a[10]=a2.z; a[11]=a2.w;
    a[12]=a3.x; a[13]=a3.y; a[14]=a3.z; a[15]=a3.w;

    float r[ED];
    #pragma unroll
    for (int j = 0; j < ED; ++j) r[j] = bl[j];
    #pragma unroll
    for (int d = 0; d < ED; ++d) {
        float av = a[d];
        #pragma unroll
        for (int j = 0; j < ED; ++j) r[j] = fmaf(av, Wl[d * ED + j], r[j]);
    }

    float ae0 = 0.f, ae1 = 0.f, ae2 = 0.f, ae3 = 0.f;
    #pragma unroll
    for (int d = 0; d < ED; ++d) {
        float rd = fmaxf(r[d], 0.f);
        ae0 = fmaf(rd, vl[d * 4 + 0], ae0);
        ae1 = fmaf(rd, vl[d * 4 + 1], ae1);
        ae2 = fmaf(rd, vl[d * 4 + 2], ae2);
        ae3 = fmaf(rd, vl[d * 4 + 3], ae3);
    }

    int src = ei[e];
    int dst = ei[EE + e];
    float4 s4 = *(const float4*)&a_src[src * 4];
    float4 d4 = *(const float4*)&a_dst[dst * 4];
    float v0 = s4.x + d4.x + ae0;
    float v1 = s4.y + d4.y + ae1;
    float v2 = s4.z + d4.z + ae2;
    float v3 = s4.w + d4.w + ae3;
    v0 = (v0 >= 0.f) ? v0 : NEGS * v0;
    v1 = (v1 >= 0.f) ? v1 : NEGS * v1;
    v2 = (v2 >= 0.f) ? v2 : NEGS * v2;
    v3 = (v3 >= 0.f) ? v3 : NEGS * v3;

    int pos = atomicAdd(off + dst, 1);
    csr_src[pos] = src;
    csr_alpha[pos] = make_float4(v0, v1, v2, v3);
}

// ---------------------------------------------------------------------------
// K6: one wave per node: online softmax over CSR edges + self-loop,
//     weighted gather of h[src], bias + residual + LayerNorm.
// ---------------------------------------------------------------------------
__global__ __launch_bounds__(256) void k_aggregate(
        const float* __restrict__ x, const float* __restrict__ hbuf,
        const float* __restrict__ a_src, const float* __restrict__ a_dst,
        const float* __restrict__ loop_sum, const int* __restrict__ cnt,
        const int* __restrict__ row_start, const int* __restrict__ csr_src,
        const float4* __restrict__ csr_alpha, const float* __restrict__ v_edge,
        const float* __restrict__ bias, const float* __restrict__ ln_g,
        const float* __restrict__ ln_b, float* __restrict__ out) {
    int t = threadIdx.x;
    int wave = t >> 6, lane = t & 63;
    int n = blockIdx.x * 4 + wave;
    if (n >= NN) return;

    int deg = cnt[n];
    int start = row_start[n];

    // ---- self-loop logit (all lanes compute identically) ----
    float inv_deg = 1.0f / fmaxf((float)deg, 1.0f);
    float al0[4];
    {
        float ae[4] = {0.f, 0.f, 0.f, 0.f};
        #pragma unroll 4
        for (int d = 0; d < ED; ++d) {
            float la = loop_sum[(long)n * ED + d] * inv_deg;
            #pragma unroll
            for (int h = 0; h < 4; ++h) ae[h] = fmaf(la, v_edge[d * 4 + h], ae[h]);
        }
        float4 s4 = *(const float4*)&a_src[n * 4];
        float4 d4 = *(const float4*)&a_dst[n * 4];
        al0[0] = s4.x + d4.x + ae[0];
        al0[1] = s4.y + d4.y + ae[1];
        al0[2] = s4.z + d4.z + ae[2];
        al0[3] = s4.w + d4.w + ae[3];
        #pragma unroll
        for (int h = 0; h < 4; ++h) al0[h] = (al0[h] >= 0.f) ? al0[h] : NEGS * al0[h];
    }

    // ---- online softmax stats over edges (lane-strided) ----
    float m[4] = {al0[0], al0[1], al0[2], al0[3]};
    float s[4] = {0.f, 0.f, 0.f, 0.f};
    for (int k = lane; k < deg; k += 64) {
        float4 a4 = csr_alpha[start + k];
        float aa[4] = {a4.x, a4.y, a4.z, a4.w};
        #pragma unroll
        for (int h = 0; h < 4; ++h) {
            float nm = fmaxf(m[h], aa[h]);
            s[h] = s[h] * __expf(m[h] - nm) + __expf(aa[h] - nm);
            m[h] = nm;
        }
    }
    #pragma unroll
    for (int d2 = 1; d2 < 64; d2 <<= 1) {
        #pragma unroll
        for (int h = 0; h < 4; ++h) {
            float mo = __shfl_xor(m[h], d2);
            float so = __shfl_xor(s[h], d2);
            float nm = fmaxf(m[h], mo);
            s[h] = s[h] * __expf(m[h] - nm) + so * __expf(mo - nm);
            m[h] = nm;
        }
    }
    #pragma unroll
    for (int h = 0; h < 4; ++h) s[h] += __expf(al0[h] - m[h]);   // self-loop term

    // lane-specific head selection: channels lane and lane+64
    int ca = lane, cb = lane + 64;
    bool hi = (lane & 32) != 0;
    float m_a = hi ? m[1] : m[0];
    float m_b = hi ? m[3] : m[2];
    float is_a = 1.0f / (hi ? s[1] : s[0]);
    float is_b = 1.0f / (hi ? s[3] : s[2]);
    float alo_a = hi ? al0[1] : al0[0];
    float alo_b = hi ? al0[3] : al0[2];

    // ---- accumulate messages ----
    float wa0 = __expf(alo_a - m_a) * is_a;
    float wb0 = __expf(alo_b - m_b) * is_b;
    float acc_a = wa0 * hbuf[(long)n * DINN + ca];
    float acc_b = wb0 * hbuf[(long)n * DINN + cb];
    for (int k = 0; k < deg; ++k) {
        int src = csr_src[start + k];
        float4 a4 = csr_alpha[start + k];
        float aa = hi ? a4.y : a4.x;
        float ab = hi ? a4.w : a4.z;
        float wa = __expf(aa - m_a) * is_a;
        float wb = __expf(ab - m_b) * is_b;
        acc_a = fmaf(wa, hbuf[(long)src * DINN + ca], acc_a);
        acc_b = fmaf(wb, hbuf[(long)src * DINN + cb], acc_b);
    }

    // ---- bias + residual + LayerNorm ----
    float oa = acc_a + bias[ca] + x[(long)n * DINN + ca];
    float ob = acc_b + bias[cb] + x[(long)n * DINN + cb];
    float sum = oa + ob, sumsq = oa * oa + ob * ob;
    #pragma unroll
    for (int d2 = 1; d2 < 64; d2 <<= 1) {
        sum   += __shfl_xor(sum, d2);
        sumsq += __shfl_xor(sumsq, d2);
    }
    float mu  = sum * (1.0f / DINN);
    float var = sumsq * (1.0f / DINN) - mu * mu;
    float rs  = rsqrtf(var + LNEPS);
    out[(long)n * DINN + ca] = (oa - mu) * rs * ln_g[ca] + ln_b[ca];
    out[(long)n * DINN + cb] = (ob - mu) * rs * ln_g[cb] + ln_b[cb];
}

// ---------------------------------------------------------------------------
extern "C" void kernel_launch(void* const* d_in, const int* in_sizes, int n_in,
                              void* d_out, int out_size, void* d_ws, size_t ws_size,
                              hipStream_t stream) {
    const float* x         = (const float*)d_in[0];
    const int*   ei        = (const int*)d_in[1];
    const float* edge_attr = (const float*)d_in[2];
    const float* W_ep      = (const float*)d_in[3];
    const float* b_ep      = (const float*)d_in[4];
    const float* W_lin     = (const float*)d_in[5];
    const float* W_edge    = (const float*)d_in[6];
    const float* att_src   = (const float*)d_in[7];
    const float* att_dst   = (const float*)d_in[8];
    const float* att_edge  = (const float*)d_in[9];
    const float* bias      = (const float*)d_in[10];
    const float* ln_g      = (const float*)d_in[11];
    const float* ln_b      = (const float*)d_in[12];
    float* out = (float*)d_out;

    char* ws = (char*)d_ws;
    size_t o = 0;
    auto take = [&](size_t bytes) -> char* {
        char* p = ws + o;
        o = (o + bytes + 255) & ~(size_t)255;
        return p;
    };
    float*  hbuf      = (float*)take((size_t)NN * DINN * 4);   // 25.6 MB
    float*  a_src     = (float*)take((size_t)NN * 4 * 4);
    float*  a_dst     = (float*)take((size_t)NN * 4 * 4);
    float*  v_edge    = (float*)take((size_t)ED * 4 * 4);
    float*  loop_sum  = (float*)take((size_t)NN * ED * 4);     // 3.2 MB (zeroed)
    int*    cnt       = (int*)  take((size_t)NN * 4);          // contiguous w/ loop_sum
    int*    row_start = (int*)  take((size_t)(NN + 1) * 4);
    int*    offv      = (int*)  take((size_t)NN * 4);
    int*    csr_src   = (int*)  take((size_t)EE * 4);          // 3.2 MB
    float4* csr_alpha = (float4*)take((size_t)EE * 16);        // 12.8 MB

    // zero loop_sum + cnt in one shot (they are contiguous: NN*ED*4 is 256B-aligned)
    hipMemsetAsync(loop_sum, 0, (size_t)NN * ED * 4 + (size_t)NN * 4, stream);

    k_precompute<<<1, 256, 0, stream>>>(W_edge, att_edge, v_edge);
    k_node<<<(NN + 63) / 64, 256, 0, stream>>>(x, W_lin, att_src, att_dst,
                                               hbuf, a_src, a_dst);
    k_edge1<<<(EE + 255) / 256, 256, 0, stream>>>(ei, edge_attr, W_ep, b_ep,
                                                  loop_sum, cnt);
    k_scan<<<1, 1024, 0, stream>>>(cnt, row_start, offv);
    k_edge2<<<(EE + 255) / 256, 256, 0, stream>>>(ei, edge_attr, W_ep, b_ep, v_edge,
                                                  a_src, a_dst, offv, csr_src, csr_alpha);
    k_aggregate<<<(NN + 3) / 4, 256, 0, stream>>>(x, hbuf, a_src, a_dst, loop_sum,
                                                  cnt, row_start, csr_src, csr_alpha,
                                                  v_edge, bias, ln_g, ln_b, out);
}

// Round 2
// 483.932 us; speedup vs baseline: 2.3542x; 2.3542x over previous
//
#include <hip/hip_runtime.h>
#include <math.h>

#define NN   50000
#define EE   800000
#define HH   4
#define CC   32
#define DINN 128
#define ED   16
#define NEGS 0.2f
#define LNEPS 1e-5f

// ---------------------------------------------------------------------------
// K1: v_edge[d][h] = sum_c W_edge[d][h*32+c] * att_edge[h][c]   (16 x 4)
// ---------------------------------------------------------------------------
__global__ void k_precompute(const float* __restrict__ W_edge,
                             const float* __restrict__ att_edge,
                             float* __restrict__ v_edge) {
    int t = threadIdx.x;
    if (t < ED * HH) {
        int d = t >> 2, h = t & 3;
        float s = 0.f;
        for (int c = 0; c < CC; ++c)
            s += W_edge[d * (HH * CC) + h * CC + c] * att_edge[h * CC + c];
        v_edge[t] = s;
    }
}

// ---------------------------------------------------------------------------
// K2: h = x @ W_lin  (N x 128), plus a_src[n][h], a_dst[n][h]
// ---------------------------------------------------------------------------
__global__ __launch_bounds__(256, 2) void k_node(
        const float* __restrict__ x, const float* __restrict__ W_lin,
        const float* __restrict__ att_src, const float* __restrict__ att_dst,
        float* __restrict__ hbuf, float* __restrict__ a_src, float* __restrict__ a_dst) {
    __shared__ float Wl[DINN * DINN];   // 64 KB
    __shared__ float xr[8 * DINN];      // 4 KB
    int t = threadIdx.x;
    for (int i = t; i < DINN * DINN; i += 256) Wl[i] = W_lin[i];

    int row0 = blockIdx.x * 64;
    int rl   = t >> 5;            // 0..7
    int j0   = (t & 31) * 4;      // 0..124
    int head = (t & 31) >> 3;     // 0..3
    int c0   = (t & 7) * 4;       // 0..28
    float4 as4 = *(const float4*)&att_src[head * CC + c0];
    float4 ad4 = *(const float4*)&att_dst[head * CC + c0];

    for (int rb = 0; rb < 64; rb += 8) {
        __syncthreads();
        long gidx = (long)(row0 + rb) * DINN + t * 4;
        float4 xv4 = make_float4(0.f, 0.f, 0.f, 0.f);
        if (gidx < (long)NN * DINN) xv4 = *(const float4*)&x[gidx];
        ((float4*)xr)[t] = xv4;
        __syncthreads();

        int row = row0 + rb + rl;
        float ax = 0.f, ay = 0.f, az = 0.f, aw = 0.f;
        #pragma unroll 16
        for (int d = 0; d < DINN; ++d) {
            float xv = xr[rl * DINN + d];
            float4 w = *(const float4*)&Wl[d * DINN + j0];
            ax = fmaf(xv, w.x, ax);
            ay = fmaf(xv, w.y, ay);
            az = fmaf(xv, w.z, az);
            aw = fmaf(xv, w.w, aw);
        }
        if (row < NN) {
            *(float4*)&hbuf[(long)row * DINN + j0] = make_float4(ax, ay, az, aw);
        }
        float ps = ax * as4.x + ay * as4.y + az * as4.z + aw * as4.w;
        float pd = ax * ad4.x + ay * ad4.y + az * ad4.z + aw * ad4.w;
        #pragma unroll
        for (int mask = 1; mask < 8; mask <<= 1) {
            ps += __shfl_xor(ps, mask);
            pd += __shfl_xor(pd, mask);
        }
        if ((t & 7) == 0 && row < NN) {
            a_src[row * 4 + head] = ps;
            a_dst[row * 4 + head] = pd;
        }
    }
}

// ---------------------------------------------------------------------------
// K3: in-degree count only (1 atomic per edge, was 17)
// ---------------------------------------------------------------------------
__global__ __launch_bounds__(256) void k_count(const int* __restrict__ ei,
                                               int* __restrict__ cnt) {
    int i = (blockIdx.x * 256 + threadIdx.x) * 4;
    if (i + 3 < EE) {
        int4 d4 = *(const int4*)(ei + EE + i);
        atomicAdd(cnt + d4.x, 1);
        atomicAdd(cnt + d4.y, 1);
        atomicAdd(cnt + d4.z, 1);
        atomicAdd(cnt + d4.w, 1);
    } else {
        for (int k = i; k < EE; ++k) atomicAdd(cnt + ei[EE + k], 1);
    }
}

// ---------------------------------------------------------------------------
// K4: exclusive scan of cnt[NN] -> row_start, off (single block, 1024 thr)
// ---------------------------------------------------------------------------
__global__ __launch_bounds__(1024) void k_scan(const int* __restrict__ cnt,
                                               int* __restrict__ row_start,
                                               int* __restrict__ off) {
    __shared__ int s[1024];
    int t = threadIdx.x;
    const int CH = (NN + 1023) / 1024;
    int i0 = t * CH;
    int i1 = i0 + CH; if (i1 > NN) i1 = NN; if (i0 > NN) i0 = NN;
    int loc = 0;
    for (int i = i0; i < i1; ++i) loc += cnt[i];
    s[t] = loc;
    __syncthreads();
    for (int d2 = 1; d2 < 1024; d2 <<= 1) {
        int v = (t >= d2) ? s[t - d2] : 0;
        __syncthreads();
        s[t] += v;
        __syncthreads();
    }
    int run = s[t] - loc;  // exclusive
    for (int i = i0; i < i1; ++i) {
        row_start[i] = run;
        off[i] = run;
        run += cnt[i];
    }
    if (t == 1023) row_start[NN] = run;
}

// ---------------------------------------------------------------------------
// K5: per edge: ea = relu(edge_attr@W_ep+b), a_e = ea.v_edge,
//     alpha = leaky(a_src[src]+a_dst[dst]+a_e), scatter into CSR slot.
//     (a_e is recoverable from alpha via inverse-leaky, so not stored)
// ---------------------------------------------------------------------------
__global__ __launch_bounds__(256) void k_edge2(
        const int* __restrict__ ei, const float* __restrict__ edge_attr,
        const float* __restrict__ W_ep, const float* __restrict__ b_ep,
        const float* __restrict__ v_edge,
        const float* __restrict__ a_src, const float* __restrict__ a_dst,
        int* __restrict__ off, int* __restrict__ csr_src,
        float4* __restrict__ csr_alpha) {
    __shared__ float Wl[ED * ED];
    __shared__ float bl[ED];
    __shared__ float vl[ED * 4];
    int t = threadIdx.x;
    if (t < ED * ED) Wl[t] = W_ep[t];
    if (t < ED) bl[t] = b_ep[t];
    if (t < ED * 4) vl[t] = v_edge[t];
    __syncthreads();

    int e = blockIdx.x * 256 + t;
    if (e >= EE) return;

    float a[ED];
    const float4* ap = (const float4*)(edge_attr + (long)e * ED);
    float4 a0 = ap[0], a1 = ap[1], a2 = ap[2], a3 = ap[3];
    a[0]=a0.x; a[1]=a0.y; a[2]=a0.z; a[3]=a0.w;
    a[4]=a1.x; a[5]=a1.y; a[6]=a1.z; a[7]=a1.w;
    a[8]=a2.x; a[9]=a2.y; a[10]=a2.z; a[11]=a2.w;
    a[12]=a3.x; a[13]=a3.y; a[14]=a3.z; a[15]=a3.w;

    float r[ED];
    #pragma unroll
    for (int j = 0; j < ED; ++j) r[j] = bl[j];
    #pragma unroll
    for (int d = 0; d < ED; ++d) {
        float av = a[d];
        #pragma unroll
        for (int j = 0; j < ED; ++j) r[j] = fmaf(av, Wl[d * ED + j], r[j]);
    }

    float ae0 = 0.f, ae1 = 0.f, ae2 = 0.f, ae3 = 0.f;
    #pragma unroll
    for (int d = 0; d < ED; ++d) {
        float rd = fmaxf(r[d], 0.f);
        ae0 = fmaf(rd, vl[d * 4 + 0], ae0);
        ae1 = fmaf(rd, vl[d * 4 + 1], ae1);
        ae2 = fmaf(rd, vl[d * 4 + 2], ae2);
        ae3 = fmaf(rd, vl[d * 4 + 3], ae3);
    }

    int src = ei[e];
    int dst = ei[EE + e];
    float4 s4 = *(const float4*)&a_src[src * 4];
    float4 d4 = *(const float4*)&a_dst[dst * 4];
    float v0 = s4.x + d4.x + ae0;
    float v1 = s4.y + d4.y + ae1;
    float v2 = s4.z + d4.z + ae2;
    float v3 = s4.w + d4.w + ae3;
    v0 = (v0 >= 0.f) ? v0 : NEGS * v0;
    v1 = (v1 >= 0.f) ? v1 : NEGS * v1;
    v2 = (v2 >= 0.f) ? v2 : NEGS * v2;
    v3 = (v3 >= 0.f) ? v3 : NEGS * v3;

    int pos = atomicAdd(off + dst, 1);
    csr_src[pos] = src;
    csr_alpha[pos] = make_float4(v0, v1, v2, v3);
}

// ---------------------------------------------------------------------------
// K6: one wave per node: stat pass recovers a_e per edge (inverse leaky) to
//     build the self-loop logit, online softmax, then weighted gather of
//     h[src], bias + residual + LayerNorm.
// ---------------------------------------------------------------------------
__global__ __launch_bounds__(256) void k_aggregate(
        const float* __restrict__ x, const float* __restrict__ hbuf,
        const float* __restrict__ a_src, const float* __restrict__ a_dst,
        const int* __restrict__ cnt, const int* __restrict__ row_start,
        const int* __restrict__ csr_src, const float4* __restrict__ csr_alpha,
        const float* __restrict__ bias, const float* __restrict__ ln_g,
        const float* __restrict__ ln_b, float* __restrict__ out) {
    int t = threadIdx.x;
    int wave = t >> 6, lane = t & 63;
    int n = blockIdx.x * 4 + wave;
    if (n >= NN) return;

    int deg = cnt[n];
    int start = row_start[n];

    float4 sn4 = *(const float4*)&a_src[n * 4];
    float4 dn4 = *(const float4*)&a_dst[n * 4];
    float ad[4] = {dn4.x, dn4.y, dn4.z, dn4.w};

    // ---- stat pass: online softmax over edges + a_e sum (lane-strided) ----
    float m[4] = {-1e30f, -1e30f, -1e30f, -1e30f};
    float s[4] = {0.f, 0.f, 0.f, 0.f};
    float aes[4] = {0.f, 0.f, 0.f, 0.f};
    for (int k = lane; k < deg; k += 64) {
        int src = csr_src[start + k];
        float4 a4 = csr_alpha[start + k];
        float4 s4 = *(const float4*)&a_src[src * 4];
        float aa[4] = {a4.x, a4.y, a4.z, a4.w};
        float sv[4] = {s4.x, s4.y, s4.z, s4.w};
        #pragma unroll
        for (int h = 0; h < 4; ++h) {
            // inverse leaky-relu to recover raw logit t, then a_e
            float tr = (aa[h] >= 0.f) ? aa[h] : 5.0f * aa[h];
            aes[h] += tr - sv[h] - ad[h];
            float nm = fmaxf(m[h], aa[h]);
            s[h] = s[h] * __expf(m[h] - nm) + __expf(aa[h] - nm);
            m[h] = nm;
        }
    }
    #pragma unroll
    for (int d2 = 1; d2 < 64; d2 <<= 1) {
        #pragma unroll
        for (int h = 0; h < 4; ++h) {
            float mo = __shfl_xor(m[h], d2);
            float so = __shfl_xor(s[h], d2);
            aes[h] += __shfl_xor(aes[h], d2);
            float nm = fmaxf(m[h], mo);
            s[h] = s[h] * __expf(m[h] - nm) + so * __expf(mo - nm);
            m[h] = nm;
        }
    }

    // ---- self-loop logit from mean a_e, fold into (m, s) ----
    float inv_deg = 1.0f / fmaxf((float)deg, 1.0f);
    float al0[4];
    float asn[4] = {sn4.x, sn4.y, sn4.z, sn4.w};
    #pragma unroll
    for (int h = 0; h < 4; ++h) {
        float v = asn[h] + ad[h] + aes[h] * inv_deg;
        v = (v >= 0.f) ? v : NEGS * v;
        al0[h] = v;
        float nm = fmaxf(m[h], v);
        s[h] = s[h] * __expf(m[h] - nm) + __expf(v - nm);
        m[h] = nm;
    }

    // lane-specific head selection: channels lane and lane+64
    int ca = lane, cb = lane + 64;
    bool hi = (lane & 32) != 0;
    float m_a = hi ? m[1] : m[0];
    float m_b = hi ? m[3] : m[2];
    float is_a = 1.0f / (hi ? s[1] : s[0]);
    float is_b = 1.0f / (hi ? s[3] : s[2]);
    float alo_a = hi ? al0[1] : al0[0];
    float alo_b = hi ? al0[3] : al0[2];

    // ---- accumulate messages ----
    float wa0 = __expf(alo_a - m_a) * is_a;
    float wb0 = __expf(alo_b - m_b) * is_b;
    float acc_a = wa0 * hbuf[(long)n * DINN + ca];
    float acc_b = wb0 * hbuf[(long)n * DINN + cb];
    for (int k = 0; k < deg; ++k) {
        int src = csr_src[start + k];
        float4 a4 = csr_alpha[start + k];
        float aa = hi ? a4.y : a4.x;
        float ab = hi ? a4.w : a4.z;
        float wa = __expf(aa - m_a) * is_a;
        float wb = __expf(ab - m_b) * is_b;
        acc_a = fmaf(wa, hbuf[(long)src * DINN + ca], acc_a);
        acc_b = fmaf(wb, hbuf[(long)src * DINN + cb], acc_b);
    }

    // ---- bias + residual + LayerNorm ----
    float oa = acc_a + bias[ca] + x[(long)n * DINN + ca];
    float ob = acc_b + bias[cb] + x[(long)n * DINN + cb];
    float sum = oa + ob, sumsq = oa * oa + ob * ob;
    #pragma unroll
    for (int d2 = 1; d2 < 64; d2 <<= 1) {
        sum   += __shfl_xor(sum, d2);
        sumsq += __shfl_xor(sumsq, d2);
    }
    float mu  = sum * (1.0f / DINN);
    float var = sumsq * (1.0f / DINN) - mu * mu;
    float rs  = rsqrtf(var + LNEPS);
    out[(long)n * DINN + ca] = (oa - mu) * rs * ln_g[ca] + ln_b[ca];
    out[(long)n * DINN + cb] = (ob - mu) * rs * ln_g[cb] + ln_b[cb];
}

// ---------------------------------------------------------------------------
extern "C" void kernel_launch(void* const* d_in, const int* in_sizes, int n_in,
                              void* d_out, int out_size, void* d_ws, size_t ws_size,
                              hipStream_t stream) {
    const float* x         = (const float*)d_in[0];
    const int*   ei        = (const int*)d_in[1];
    const float* edge_attr = (const float*)d_in[2];
    const float* W_ep      = (const float*)d_in[3];
    const float* b_ep      = (const float*)d_in[4];
    const float* W_lin     = (const float*)d_in[5];
    const float* W_edge    = (const float*)d_in[6];
    const float* att_src   = (const float*)d_in[7];
    const float* att_dst   = (const float*)d_in[8];
    const float* att_edge  = (const float*)d_in[9];
    const float* bias      = (const float*)d_in[10];
    const float* ln_g      = (const float*)d_in[11];
    const float* ln_b      = (const float*)d_in[12];
    float* out = (float*)d_out;

    char* ws = (char*)d_ws;
    size_t o = 0;
    auto take = [&](size_t bytes) -> char* {
        char* p = ws + o;
        o = (o + bytes + 255) & ~(size_t)255;
        return p;
    };
    float*  hbuf      = (float*)take((size_t)NN * DINN * 4);   // 25.6 MB
    float*  a_src     = (float*)take((size_t)NN * 4 * 4);
    float*  a_dst     = (float*)take((size_t)NN * 4 * 4);
    float*  v_edge    = (float*)take((size_t)ED * 4 * 4);
    int*    cnt       = (int*)  take((size_t)NN * 4);          // zeroed
    int*    row_start = (int*)  take((size_t)(NN + 1) * 4);
    int*    offv      = (int*)  take((size_t)NN * 4);
    int*    csr_src   = (int*)  take((size_t)EE * 4);          // 3.2 MB
    float4* csr_alpha = (float4*)take((size_t)EE * 16);        // 12.8 MB

    hipMemsetAsync(cnt, 0, (size_t)NN * 4, stream);

    k_precompute<<<1, 256, 0, stream>>>(W_edge, att_edge, v_edge);
    k_node<<<(NN + 63) / 64, 256, 0, stream>>>(x, W_lin, att_src, att_dst,
                                               hbuf, a_src, a_dst);
    k_count<<<(EE / 4 + 255) / 256, 256, 0, stream>>>(ei, cnt);
    k_scan<<<1, 1024, 0, stream>>>(cnt, row_start, offv);
    k_edge2<<<(EE + 255) / 256, 256, 0, stream>>>(ei, edge_attr, W_ep, b_ep, v_edge,
                                                  a_src, a_dst, offv, csr_src, csr_alpha);
    k_aggregate<<<(NN + 3) / 4, 256, 0, stream>>>(x, hbuf, a_src, a_dst,
                                                  cnt, row_start, csr_src, csr_alpha,
                                                  bias, ln_g, ln_b, out);
}

// Round 3
// 405.909 us; speedup vs baseline: 2.8067x; 1.1922x over previous
//
#include <hip/hip_runtime.h>
#include <hip/hip_fp16.h>
#include <math.h>

#define NN   50000
#define EE   800000
#define HH   4
#define CC   32
#define DINN 128
#define ED   16
#define NEGS 0.2f
#define LNEPS 1e-5f

// Per-edge CSR record: exp(alpha) per head, a_e per head (half), src. 32 B.
struct __align__(16) Rec {
    float4  expa;
    __half2 ae01;
    __half2 ae23;
    int     src;
    int     pad;
};

// ---------------------------------------------------------------------------
// K2: h = x @ W_lin  (N x 128), plus a_src[n][h], a_dst[n][h]
// 32-row x 128-col tile / block; thread = 4 rows x 4 cols (16 acc).
// LDS: W 64KB + x-tile 16KB = 80KB -> 2 blocks/CU.
// ---------------------------------------------------------------------------
__global__ __launch_bounds__(256, 2) void k_node(
        const float* __restrict__ x, const float* __restrict__ W_lin,
        const float* __restrict__ att_src, const float* __restrict__ att_dst,
        float* __restrict__ hbuf, float* __restrict__ a_src, float* __restrict__ a_dst) {
    __shared__ float Wl[DINN * DINN];   // 64 KB
    __shared__ float xr[32 * DINN];     // 16 KB
    int t = threadIdx.x;

    {   // stage W (4096 float4)
        const float4* Wg = (const float4*)W_lin;
        float4* Ws = (float4*)Wl;
        #pragma unroll
        for (int i = 0; i < 16; ++i) Ws[t + 256 * i] = Wg[t + 256 * i];
    }
    int row0 = blockIdx.x * 32;
    {   // stage 32 rows of x (1024 float4)
        const float4* xg = (const float4*)x;
        float4* xs = (float4*)xr;
        #pragma unroll
        for (int i = 0; i < 4; ++i) {
            int idx = t + 256 * i;              // 0..1023
            int row = row0 + (idx >> 5);
            float4 v = make_float4(0.f, 0.f, 0.f, 0.f);
            if (row < NN) v = xg[(long)row * 32 + (idx & 31)];
            xs[idx] = v;
        }
    }
    __syncthreads();

    int cg = t & 31, rg = t >> 5;
    int j0 = cg * 4;
    float acc[4][4] = {};
    #pragma unroll 4
    for (int k = 0; k < DINN; ++k) {
        float4 w = *(const float4*)&Wl[k * DINN + j0];
        #pragma unroll
        for (int i = 0; i < 4; ++i) {
            float xv = xr[(rg * 4 + i) * DINN + k];
            acc[i][0] = fmaf(xv, w.x, acc[i][0]);
            acc[i][1] = fmaf(xv, w.y, acc[i][1]);
            acc[i][2] = fmaf(xv, w.z, acc[i][2]);
            acc[i][3] = fmaf(xv, w.w, acc[i][3]);
        }
    }

    int head = cg >> 3, c0 = (cg & 7) * 4;
    float4 as4 = *(const float4*)&att_src[head * CC + c0];
    float4 ad4 = *(const float4*)&att_dst[head * CC + c0];
    #pragma unroll
    for (int i = 0; i < 4; ++i) {
        int row = row0 + rg * 4 + i;
        if (row < NN)
            *(float4*)&hbuf[(long)row * DINN + j0] =
                make_float4(acc[i][0], acc[i][1], acc[i][2], acc[i][3]);
        float ps = acc[i][0] * as4.x + acc[i][1] * as4.y + acc[i][2] * as4.z + acc[i][3] * as4.w;
        float pd = acc[i][0] * ad4.x + acc[i][1] * ad4.y + acc[i][2] * ad4.z + acc[i][3] * ad4.w;
        #pragma unroll
        for (int mask = 1; mask < 8; mask <<= 1) {
            ps += __shfl_xor(ps, mask);
            pd += __shfl_xor(pd, mask);
        }
        if ((cg & 7) == 0 && row < NN) {
            a_src[row * 4 + head] = ps;
            a_dst[row * 4 + head] = pd;
        }
    }
}

// ---------------------------------------------------------------------------
// K3: in-degree count; atomic return value IS the CSR rank (dedups the
// cursor atomic that k_edge2 used to pay).
// ---------------------------------------------------------------------------
__global__ __launch_bounds__(256) void k_count(const int* __restrict__ ei,
                                               int* __restrict__ cnt,
                                               int* __restrict__ rank) {
    int e = blockIdx.x * 256 + threadIdx.x;
    if (e < EE) rank[e] = atomicAdd(cnt + ei[EE + e], 1);
}

// ---------------------------------------------------------------------------
// K4: exclusive scan of cnt[NN] -> row_start; also folds v_edge precompute
// (v_edge[d][h] = sum_c W_edge[d][h*32+c]*att_edge[h][c]).
// ---------------------------------------------------------------------------
__global__ __launch_bounds__(1024) void k_scan(const int* __restrict__ cnt,
                                               int* __restrict__ row_start,
                                               const float* __restrict__ W_edge,
                                               const float* __restrict__ att_edge,
                                               float* __restrict__ v_edge) {
    int t = threadIdx.x;
    if (t < ED * HH) {
        int d = t >> 2, h = t & 3;
        float s = 0.f;
        for (int c = 0; c < CC; ++c)
            s += W_edge[d * (HH * CC) + h * CC + c] * att_edge[h * CC + c];
        v_edge[t] = s;
    }
    __shared__ int s[1024];
    const int CH = (NN + 1023) / 1024;
    int i0 = t * CH;
    int i1 = i0 + CH; if (i1 > NN) i1 = NN; if (i0 > NN) i0 = NN;
    int loc = 0;
    for (int i = i0; i < i1; ++i) loc += cnt[i];
    s[t] = loc;
    __syncthreads();
    for (int d2 = 1; d2 < 1024; d2 <<= 1) {
        int v = (t >= d2) ? s[t - d2] : 0;
        __syncthreads();
        s[t] += v;
        __syncthreads();
    }
    int run = s[t] - loc;  // exclusive
    for (int i = i0; i < i1; ++i) {
        row_start[i] = run;
        run += cnt[i];
    }
    if (t == 1023) row_start[NN] = run;
}

// ---------------------------------------------------------------------------
// K5: per edge: ea = relu(edge_attr@W_ep+b), a_e = ea.v_edge,
//     alpha = leaky(a_src[src]+a_dst[dst]+a_e).
//     Store ONE 32B record {exp(alpha)x4, a_e(half)x4, src} at
//     row_start[dst] + rank[e]  (atomic-free, single cache line).
// ---------------------------------------------------------------------------
__global__ __launch_bounds__(256) void k_edge2(
        const int* __restrict__ ei, const float* __restrict__ edge_attr,
        const float* __restrict__ W_ep, const float* __restrict__ b_ep,
        const float* __restrict__ v_edge,
        const float* __restrict__ a_src, const float* __restrict__ a_dst,
        const int* __restrict__ row_start, const int* __restrict__ rank,
        Rec* __restrict__ rec) {
    __shared__ float Wl[ED * ED];
    __shared__ float bl[ED];
    __shared__ float vl[ED * 4];
    int t = threadIdx.x;
    if (t < ED * ED) Wl[t] = W_ep[t];
    if (t < ED) bl[t] = b_ep[t];
    if (t < ED * 4) vl[t] = v_edge[t];
    __syncthreads();

    int e = blockIdx.x * 256 + t;
    if (e >= EE) return;

    float a[ED];
    const float4* ap = (const float4*)(edge_attr + (long)e * ED);
    float4 a0 = ap[0], a1 = ap[1], a2 = ap[2], a3 = ap[3];
    a[0]=a0.x; a[1]=a0.y; a[2]=a0.z; a[3]=a0.w;
    a[4]=a1.x; a[5]=a1.y; a[6]=a1.z; a[7]=a1.w;
    a[8]=a2.x; a[9]=a2.y; a[10]=a2.z; a[11]=a2.w;
    a[12]=a3.x; a[13]=a3.y; a[14]=a3.z; a[15]=a3.w;

    float r[ED];
    #pragma unroll
    for (int j = 0; j < ED; ++j) r[j] = bl[j];
    #pragma unroll
    for (int d = 0; d < ED; ++d) {
        float av = a[d];
        #pragma unroll
        for (int j = 0; j < ED; ++j) r[j] = fmaf(av, Wl[d * ED + j], r[j]);
    }

    float ae0 = 0.f, ae1 = 0.f, ae2 = 0.f, ae3 = 0.f;
    #pragma unroll
    for (int d = 0; d < ED; ++d) {
        float rd = fmaxf(r[d], 0.f);
        ae0 = fmaf(rd, vl[d * 4 + 0], ae0);
        ae1 = fmaf(rd, vl[d * 4 + 1], ae1);
        ae2 = fmaf(rd, vl[d * 4 + 2], ae2);
        ae3 = fmaf(rd, vl[d * 4 + 3], ae3);
    }

    int src = ei[e];
    int dst = ei[EE + e];
    float4 s4 = *(const float4*)&a_src[src * 4];
    float4 d4 = *(const float4*)&a_dst[dst * 4];
    float v0 = s4.x + d4.x + ae0;
    float v1 = s4.y + d4.y + ae1;
    float v2 = s4.z + d4.z + ae2;
    float v3 = s4.w + d4.w + ae3;
    v0 = (v0 >= 0.f) ? v0 : NEGS * v0;
    v1 = (v1 >= 0.f) ? v1 : NEGS * v1;
    v2 = (v2 >= 0.f) ? v2 : NEGS * v2;
    v3 = (v3 >= 0.f) ? v3 : NEGS * v3;

    Rec rc;
    rc.expa = make_float4(__expf(v0), __expf(v1), __expf(v2), __expf(v3));
    rc.ae01 = __floats2half2_rn(ae0, ae1);
    rc.ae23 = __floats2half2_rn(ae2, ae3);
    rc.src  = src;
    rc.pad  = 0;
    rec[row_start[dst] + rank[e]] = rc;
}

// ---------------------------------------------------------------------------
// K6: one wave per node. Stat pass: coalesced sum of exp(alpha) and a_e
// (no max needed: |alpha| ~ 1). Self-loop logit from mean a_e. Accumulate:
// unnormalized weighted gather of h[src] (no transcendentals in loop),
// scale by 1/s at end, then bias + residual + LayerNorm.
// ---------------------------------------------------------------------------
__global__ __launch_bounds__(256) void k_aggregate(
        const float* __restrict__ x, const float* __restrict__ hbuf,
        const float* __restrict__ a_src, const float* __restrict__ a_dst,
        const int* __restrict__ row_start, const Rec* __restrict__ rec,
        const float* __restrict__ bias, const float* __restrict__ ln_g,
        const float* __restrict__ ln_b, float* __restrict__ out) {
    int t = threadIdx.x;
    int wave = t >> 6, lane = t & 63;
    int n = blockIdx.x * 4 + wave;
    if (n >= NN) return;

    int start = row_start[n];
    int deg   = row_start[n + 1] - start;

    // ---- stat pass: sum exp(alpha) and a_e, lane-strided, coalesced ----
    float s[4]   = {0.f, 0.f, 0.f, 0.f};
    float aes[4] = {0.f, 0.f, 0.f, 0.f};
    for (int k = lane; k < deg; k += 64) {
        Rec r = rec[start + k];
        s[0] += r.expa.x; s[1] += r.expa.y; s[2] += r.expa.z; s[3] += r.expa.w;
        float2 a01 = __half22float2(r.ae01);
        float2 a23 = __half22float2(r.ae23);
        aes[0] += a01.x; aes[1] += a01.y; aes[2] += a23.x; aes[3] += a23.y;
    }
    #pragma unroll
    for (int d2 = 1; d2 < 64; d2 <<= 1) {
        #pragma unroll
        for (int h = 0; h < 4; ++h) {
            s[h]   += __shfl_xor(s[h], d2);
            aes[h] += __shfl_xor(aes[h], d2);
        }
    }

    // ---- self-loop logit from mean a_e ----
    float4 sn4 = *(const float4*)&a_src[n * 4];
    float4 dn4 = *(const float4*)&a_dst[n * 4];
    float asn[4] = {sn4.x, sn4.y, sn4.z, sn4.w};
    float adn[4] = {dn4.x, dn4.y, dn4.z, dn4.w};
    float inv_deg = 1.0f / fmaxf((float)deg, 1.0f);
    float w0[4];
    #pragma unroll
    for (int h = 0; h < 4; ++h) {
        float v = asn[h] + adn[h] + aes[h] * inv_deg;
        v = (v >= 0.f) ? v : NEGS * v;
        w0[h] = __expf(v);
        s[h] += w0[h];
    }

    // lane-specific head selection: channels lane and lane+64
    int ca = lane, cb = lane + 64;
    bool hi = (lane & 32) != 0;
    float is_a = 1.0f / (hi ? s[1] : s[0]);
    float is_b = 1.0f / (hi ? s[3] : s[2]);
    float wa0  = hi ? w0[1] : w0[0];
    float wb0  = hi ? w0[3] : w0[2];

    // ---- accumulate messages (unnormalized; no exp in loop) ----
    float acc_a = wa0 * hbuf[(long)n * DINN + ca];
    float acc_b = wb0 * hbuf[(long)n * DINN + cb];
    for (int k = 0; k < deg; ++k) {
        const Rec* rp = rec + start + k;
        float4 e4 = rp->expa;
        int   src = rp->src;
        float wa = hi ? e4.y : e4.x;
        float wb = hi ? e4.w : e4.z;
        acc_a = fmaf(wa, hbuf[(long)src * DINN + ca], acc_a);
        acc_b = fmaf(wb, hbuf[(long)src * DINN + cb], acc_b);
    }
    acc_a *= is_a;
    acc_b *= is_b;

    // ---- bias + residual + LayerNorm ----
    float oa = acc_a + bias[ca] + x[(long)n * DINN + ca];
    float ob = acc_b + bias[cb] + x[(long)n * DINN + cb];
    float sum = oa + ob, sumsq = oa * oa + ob * ob;
    #pragma unroll
    for (int d2 = 1; d2 < 64; d2 <<= 1) {
        sum   += __shfl_xor(sum, d2);
        sumsq += __shfl_xor(sumsq, d2);
    }
    float mu  = sum * (1.0f / DINN);
    float var = sumsq * (1.0f / DINN) - mu * mu;
    float rs  = rsqrtf(var + LNEPS);
    out[(long)n * DINN + ca] = (oa - mu) * rs * ln_g[ca] + ln_b[ca];
    out[(long)n * DINN + cb] = (ob - mu) * rs * ln_g[cb] + ln_b[cb];
}

// ---------------------------------------------------------------------------
extern "C" void kernel_launch(void* const* d_in, const int* in_sizes, int n_in,
                              void* d_out, int out_size, void* d_ws, size_t ws_size,
                              hipStream_t stream) {
    const float* x         = (const float*)d_in[0];
    const int*   ei        = (const int*)d_in[1];
    const float* edge_attr = (const float*)d_in[2];
    const float* W_ep      = (const float*)d_in[3];
    const float* b_ep      = (const float*)d_in[4];
    const float* W_lin     = (const float*)d_in[5];
    const float* W_edge    = (const float*)d_in[6];
    const float* att_src   = (const float*)d_in[7];
    const float* att_dst   = (const float*)d_in[8];
    const float* att_edge  = (const float*)d_in[9];
    const float* bias      = (const float*)d_in[10];
    const float* ln_g      = (const float*)d_in[11];
    const float* ln_b      = (const float*)d_in[12];
    float* out = (float*)d_out;

    char* ws = (char*)d_ws;
    size_t o = 0;
    auto take = [&](size_t bytes) -> char* {
        char* p = ws + o;
        o = (o + bytes + 255) & ~(size_t)255;
        return p;
    };
    float*  hbuf      = (float*)take((size_t)NN * DINN * 4);   // 25.6 MB
    float*  a_src     = (float*)take((size_t)NN * 4 * 4);
    float*  a_dst     = (float*)take((size_t)NN * 4 * 4);
    float*  v_edge    = (float*)take((size_t)ED * 4 * 4);
    int*    cnt       = (int*)  take((size_t)NN * 4);          // zeroed
    int*    row_start = (int*)  take((size_t)(NN + 1) * 4);
    int*    rank      = (int*)  take((size_t)EE * 4);          // 3.2 MB
    Rec*    rec       = (Rec*)  take((size_t)EE * sizeof(Rec)); // 25.6 MB

    hipMemsetAsync(cnt, 0, (size_t)NN * 4, stream);

    k_node<<<(NN + 31) / 32, 256, 0, stream>>>(x, W_lin, att_src, att_dst,
                                               hbuf, a_src, a_dst);
    k_count<<<(EE + 255) / 256, 256, 0, stream>>>(ei, cnt, rank);
    k_scan<<<1, 1024, 0, stream>>>(cnt, row_start, W_edge, att_edge, v_edge);
    k_edge2<<<(EE + 255) / 256, 256, 0, stream>>>(ei, edge_attr, W_ep, b_ep, v_edge,
                                                  a_src, a_dst, row_start, rank, rec);
    k_aggregate<<<(NN + 3) / 4, 256, 0, stream>>>(x, hbuf, a_src, a_dst,
                                                  row_start, rec,
                                                  bias, ln_g, ln_b, out);
}

// Round 4
// 369.494 us; speedup vs baseline: 3.0834x; 1.0986x over previous
//
#include <hip/hip_runtime.h>
#include <hip/hip_fp16.h>
#include <math.h>

#define NN   50000
#define EE   800000
#define HH   4
#define CC   32
#define DINN 128
#define ED   16
#define NEGS 0.2f
#define LNEPS 1e-5f

// Per-edge CSR record: exp(alpha) per head, a_e per head (half), src. 32 B.
struct __align__(16) Rec {
    float4  expa;
    __half2 ae01;
    __half2 ae23;
    int     src;
    int     pad;
};

struct __align__(8) Hp { __half2 a, b; };

// ---------------------------------------------------------------------------
// K2: h = x @ W_lin (N x 128) -> hbuf in fp16, plus a_src[n][h], a_dst[n][h]
// 32-row x 128-col tile / block; thread = 4 rows x 4 cols (16 acc).
// ---------------------------------------------------------------------------
__global__ __launch_bounds__(256, 2) void k_node(
        const float* __restrict__ x, const float* __restrict__ W_lin,
        const float* __restrict__ att_src, const float* __restrict__ att_dst,
        __half* __restrict__ hb, float* __restrict__ a_src, float* __restrict__ a_dst) {
    __shared__ float Wl[DINN * DINN];   // 64 KB
    __shared__ float xr[32 * DINN];     // 16 KB
    int t = threadIdx.x;

    {   // stage W (4096 float4)
        const float4* Wg = (const float4*)W_lin;
        float4* Ws = (float4*)Wl;
        #pragma unroll
        for (int i = 0; i < 16; ++i) Ws[t + 256 * i] = Wg[t + 256 * i];
    }
    int row0 = blockIdx.x * 32;
    {   // stage 32 rows of x (1024 float4)
        const float4* xg = (const float4*)x;
        float4* xs = (float4*)xr;
        #pragma unroll
        for (int i = 0; i < 4; ++i) {
            int idx = t + 256 * i;              // 0..1023
            int row = row0 + (idx >> 5);
            float4 v = make_float4(0.f, 0.f, 0.f, 0.f);
            if (row < NN) v = xg[(long)row * 32 + (idx & 31)];
            xs[idx] = v;
        }
    }
    __syncthreads();

    int cg = t & 31, rg = t >> 5;
    int j0 = cg * 4;
    float acc[4][4] = {};
    #pragma unroll 4
    for (int k = 0; k < DINN; ++k) {
        float4 w = *(const float4*)&Wl[k * DINN + j0];
        #pragma unroll
        for (int i = 0; i < 4; ++i) {
            float xv = xr[(rg * 4 + i) * DINN + k];
            acc[i][0] = fmaf(xv, w.x, acc[i][0]);
            acc[i][1] = fmaf(xv, w.y, acc[i][1]);
            acc[i][2] = fmaf(xv, w.z, acc[i][2]);
            acc[i][3] = fmaf(xv, w.w, acc[i][3]);
        }
    }

    int head = cg >> 3, c0 = (cg & 7) * 4;
    float4 as4 = *(const float4*)&att_src[head * CC + c0];
    float4 ad4 = *(const float4*)&att_dst[head * CC + c0];
    #pragma unroll
    for (int i = 0; i < 4; ++i) {
        int row = row0 + rg * 4 + i;
        if (row < NN) {
            Hp p;
            p.a = __floats2half2_rn(acc[i][0], acc[i][1]);
            p.b = __floats2half2_rn(acc[i][2], acc[i][3]);
            *(Hp*)&hb[(long)row * DINN + j0] = p;
        }
        float ps = acc[i][0] * as4.x + acc[i][1] * as4.y + acc[i][2] * as4.z + acc[i][3] * as4.w;
        float pd = acc[i][0] * ad4.x + acc[i][1] * ad4.y + acc[i][2] * ad4.z + acc[i][3] * ad4.w;
        #pragma unroll
        for (int mask = 1; mask < 8; mask <<= 1) {
            ps += __shfl_xor(ps, mask);
            pd += __shfl_xor(pd, mask);
        }
        if ((cg & 7) == 0 && row < NN) {
            a_src[row * 4 + head] = ps;
            a_dst[row * 4 + head] = pd;
        }
    }
}

// ---------------------------------------------------------------------------
// K3: in-degree count; atomic return value IS the CSR rank.
// ---------------------------------------------------------------------------
__global__ __launch_bounds__(256) void k_count(const int* __restrict__ ei,
                                               int* __restrict__ cnt,
                                               int* __restrict__ rank) {
    int e = blockIdx.x * 256 + threadIdx.x;
    if (e < EE) rank[e] = atomicAdd(cnt + ei[EE + e], 1);
}

// ---------------------------------------------------------------------------
// K4: exclusive scan of cnt[NN] -> row_start; also folds v_edge precompute.
// ---------------------------------------------------------------------------
__global__ __launch_bounds__(1024) void k_scan(const int* __restrict__ cnt,
                                               int* __restrict__ row_start,
                                               const float* __restrict__ W_edge,
                                               const float* __restrict__ att_edge,
                                               float* __restrict__ v_edge) {
    int t = threadIdx.x;
    if (t < ED * HH) {
        int d = t >> 2, h = t & 3;
        float s = 0.f;
        for (int c = 0; c < CC; ++c)
            s += W_edge[d * (HH * CC) + h * CC + c] * att_edge[h * CC + c];
        v_edge[t] = s;
    }
    __shared__ int s[1024];
    const int CH = (NN + 1023) / 1024;
    int i0 = t * CH;
    int i1 = i0 + CH; if (i1 > NN) i1 = NN; if (i0 > NN) i0 = NN;
    int loc = 0;
    for (int i = i0; i < i1; ++i) loc += cnt[i];
    s[t] = loc;
    __syncthreads();
    for (int d2 = 1; d2 < 1024; d2 <<= 1) {
        int v = (t >= d2) ? s[t - d2] : 0;
        __syncthreads();
        s[t] += v;
        __syncthreads();
    }
    int run = s[t] - loc;  // exclusive
    for (int i = i0; i < i1; ++i) {
        row_start[i] = run;
        run += cnt[i];
    }
    if (t == 1023) row_start[NN] = run;
}

// ---------------------------------------------------------------------------
// K5: per edge: ea = relu(edge_attr@W_ep+b), a_e = ea.v_edge,
//     alpha = leaky(a_src[src]+a_dst[dst]+a_e).
//     Store ONE 32B record at row_start[dst]+rank[e] (atomic-free).
// ---------------------------------------------------------------------------
__global__ __launch_bounds__(256) void k_edge2(
        const int* __restrict__ ei, const float* __restrict__ edge_attr,
        const float* __restrict__ W_ep, const float* __restrict__ b_ep,
        const float* __restrict__ v_edge,
        const float* __restrict__ a_src, const float* __restrict__ a_dst,
        const int* __restrict__ row_start, const int* __restrict__ rank,
        Rec* __restrict__ rec) {
    __shared__ float Wl[ED * ED];
    __shared__ float bl[ED];
    __shared__ float vl[ED * 4];
    int t = threadIdx.x;
    if (t < ED * ED) Wl[t] = W_ep[t];
    if (t < ED) bl[t] = b_ep[t];
    if (t < ED * 4) vl[t] = v_edge[t];
    __syncthreads();

    int e = blockIdx.x * 256 + t;
    if (e >= EE) return;

    float a[ED];
    const float4* ap = (const float4*)(edge_attr + (long)e * ED);
    float4 a0 = ap[0], a1 = ap[1], a2 = ap[2], a3 = ap[3];
    a[0]=a0.x; a[1]=a0.y; a[2]=a0.z; a[3]=a0.w;
    a[4]=a1.x; a[5]=a1.y; a[6]=a1.z; a[7]=a1.w;
    a[8]=a2.x; a[9]=a2.y; a[10]=a2.z; a[11]=a2.w;
    a[12]=a3.x; a[13]=a3.y; a[14]=a3.z; a[15]=a3.w;

    float r[ED];
    #pragma unroll
    for (int j = 0; j < ED; ++j) r[j] = bl[j];
    #pragma unroll
    for (int d = 0; d < ED; ++d) {
        float av = a[d];
        #pragma unroll
        for (int j = 0; j < ED; ++j) r[j] = fmaf(av, Wl[d * ED + j], r[j]);
    }

    float ae0 = 0.f, ae1 = 0.f, ae2 = 0.f, ae3 = 0.f;
    #pragma unroll
    for (int d = 0; d < ED; ++d) {
        float rd = fmaxf(r[d], 0.f);
        ae0 = fmaf(rd, vl[d * 4 + 0], ae0);
        ae1 = fmaf(rd, vl[d * 4 + 1], ae1);
        ae2 = fmaf(rd, vl[d * 4 + 2], ae2);
        ae3 = fmaf(rd, vl[d * 4 + 3], ae3);
    }

    int src = ei[e];
    int dst = ei[EE + e];
    float4 s4 = *(const float4*)&a_src[src * 4];
    float4 d4 = *(const float4*)&a_dst[dst * 4];
    float v0 = s4.x + d4.x + ae0;
    float v1 = s4.y + d4.y + ae1;
    float v2 = s4.z + d4.z + ae2;
    float v3 = s4.w + d4.w + ae3;
    v0 = (v0 >= 0.f) ? v0 : NEGS * v0;
    v1 = (v1 >= 0.f) ? v1 : NEGS * v1;
    v2 = (v2 >= 0.f) ? v2 : NEGS * v2;
    v3 = (v3 >= 0.f) ? v3 : NEGS * v3;

    Rec rc;
    rc.expa = make_float4(__expf(v0), __expf(v1), __expf(v2), __expf(v3));
    rc.ae01 = __floats2half2_rn(ae0, ae1);
    rc.ae23 = __floats2half2_rn(ae2, ae3);
    rc.src  = src;
    rc.pad  = 0;
    rec[row_start[dst] + rank[e]] = rc;
}

// ---------------------------------------------------------------------------
// K6: one wave per node, SINGLE pass. Each lane owns channels {2*lane,
// 2*lane+1} (one head per lane); every lane walks all edges, so per-lane
// running sums of exp(alpha) and a_e for its own head are complete totals —
// no separate stat pass, no cross-lane softmax reduction. 4-wide unroll
// keeps 4 independent half2 gathers in flight.
// ---------------------------------------------------------------------------
__global__ __launch_bounds__(256) void k_aggregate(
        const float* __restrict__ x, const __half2* __restrict__ hb,
        const float* __restrict__ a_src, const float* __restrict__ a_dst,
        const int* __restrict__ row_start, const Rec* __restrict__ rec,
        const float* __restrict__ bias, const float* __restrict__ ln_g,
        const float* __restrict__ ln_b, float* __restrict__ out) {
    int t = threadIdx.x;
    int wave = t >> 6, lane = t & 63;
    int n = blockIdx.x * 4 + wave;
    if (n >= NN) return;

    int start = row_start[n];
    int deg   = row_start[n + 1] - start;

    bool h1 = (lane & 32) != 0;   // head >= 2
    bool h0 = (lane & 16) != 0;   // head odd
    float accx = 0.f, accy = 0.f, s_own = 0.f, aes_own = 0.f;

    auto doEdge = [&](const Rec& r, __half2 hv) {
        float4 e4 = r.expa;
        float2 ef = h1 ? make_float2(e4.z, e4.w) : make_float2(e4.x, e4.y);
        float w = h0 ? ef.y : ef.x;
        float2 aef = __half22float2(h1 ? r.ae23 : r.ae01);
        aes_own += h0 ? aef.y : aef.x;
        s_own += w;
        float2 hf = __half22float2(hv);
        accx = fmaf(w, hf.x, accx);
        accy = fmaf(w, hf.y, accy);
    };

    const Rec* rp = rec + start;
    int k = 0;
    for (; k + 4 <= deg; k += 4) {
        Rec r0 = rp[k], r1 = rp[k + 1], r2 = rp[k + 2], r3 = rp[k + 3];
        __half2 v0 = hb[(long)r0.src * 64 + lane];
        __half2 v1 = hb[(long)r1.src * 64 + lane];
        __half2 v2 = hb[(long)r2.src * 64 + lane];
        __half2 v3 = hb[(long)r3.src * 64 + lane];
        doEdge(r0, v0); doEdge(r1, v1); doEdge(r2, v2); doEdge(r3, v3);
    }
    for (; k < deg; ++k) {
        Rec r = rp[k];
        doEdge(r, hb[(long)r.src * 64 + lane]);
    }

    // ---- self-loop from mean a_e (per-lane totals are complete) ----
    int head = lane >> 4;
    float inv_deg = 1.0f / fmaxf((float)deg, 1.0f);
    float v = a_src[n * 4 + head] + a_dst[n * 4 + head] + aes_own * inv_deg;
    v = (v >= 0.f) ? v : NEGS * v;
    float w0 = __expf(v);
    s_own += w0;
    float2 hn = __half22float2(hb[(long)n * 64 + lane]);
    accx = fmaf(w0, hn.x, accx);
    accy = fmaf(w0, hn.y, accy);
    float is = 1.0f / s_own;
    accx *= is; accy *= is;

    // ---- bias + residual + LayerNorm (channels c0, c0+1) ----
    int c0 = lane * 2;
    float2 b2 = *(const float2*)&bias[c0];
    float2 x2 = *(const float2*)&x[(long)n * DINN + c0];
    float oa = accx + b2.x + x2.x;
    float ob = accy + b2.y + x2.y;
    float sum = oa + ob, sumsq = oa * oa + ob * ob;
    #pragma unroll
    for (int d2 = 1; d2 < 64; d2 <<= 1) {
        sum   += __shfl_xor(sum, d2);
        sumsq += __shfl_xor(sumsq, d2);
    }
    float mu  = sum * (1.0f / DINN);
    float var = sumsq * (1.0f / DINN) - mu * mu;
    float rs  = rsqrtf(var + LNEPS);
    float2 g2  = *(const float2*)&ln_g[c0];
    float2 lb2 = *(const float2*)&ln_b[c0];
    float2 o2;
    o2.x = (oa - mu) * rs * g2.x + lb2.x;
    o2.y = (ob - mu) * rs * g2.y + lb2.y;
    *(float2*)&out[(long)n * DINN + c0] = o2;
}

// ---------------------------------------------------------------------------
extern "C" void kernel_launch(void* const* d_in, const int* in_sizes, int n_in,
                              void* d_out, int out_size, void* d_ws, size_t ws_size,
                              hipStream_t stream) {
    const float* x         = (const float*)d_in[0];
    const int*   ei        = (const int*)d_in[1];
    const float* edge_attr = (const float*)d_in[2];
    const float* W_ep      = (const float*)d_in[3];
    const float* b_ep      = (const float*)d_in[4];
    const float* W_lin     = (const float*)d_in[5];
    const float* W_edge    = (const float*)d_in[6];
    const float* att_src   = (const float*)d_in[7];
    const float* att_dst   = (const float*)d_in[8];
    const float* att_edge  = (const float*)d_in[9];
    const float* bias      = (const float*)d_in[10];
    const float* ln_g      = (const float*)d_in[11];
    const float* ln_b      = (const float*)d_in[12];
    float* out = (float*)d_out;

    char* ws = (char*)d_ws;
    size_t o = 0;
    auto take = [&](size_t bytes) -> char* {
        char* p = ws + o;
        o = (o + bytes + 255) & ~(size_t)255;
        return p;
    };
    __half* hbuf      = (__half*)take((size_t)NN * DINN * 2);  // 12.8 MB
    float*  a_src     = (float*)take((size_t)NN * 4 * 4);
    float*  a_dst     = (float*)take((size_t)NN * 4 * 4);
    float*  v_edge    = (float*)take((size_t)ED * 4 * 4);
    int*    cnt       = (int*)  take((size_t)NN * 4);          // zeroed
    int*    row_start = (int*)  take((size_t)(NN + 1) * 4);
    int*    rank      = (int*)  take((size_t)EE * 4);          // 3.2 MB
    Rec*    rec       = (Rec*)  take((size_t)EE * sizeof(Rec)); // 25.6 MB

    hipMemsetAsync(cnt, 0, (size_t)NN * 4, stream);

    k_node<<<(NN + 31) / 32, 256, 0, stream>>>(x, W_lin, att_src, att_dst,
                                               hbuf, a_src, a_dst);
    k_count<<<(EE + 255) / 256, 256, 0, stream>>>(ei, cnt, rank);
    k_scan<<<1, 1024, 0, stream>>>(cnt, row_start, W_edge, att_edge, v_edge);
    k_edge2<<<(EE + 255) / 256, 256, 0, stream>>>(ei, edge_attr, W_ep, b_ep, v_edge,
                                                  a_src, a_dst, row_start, rank, rec);
    k_aggregate<<<(NN + 3) / 4, 256, 0, stream>>>(x, (const __half2*)hbuf,
                                                  a_src, a_dst, row_start, rec,
                                                  bias, ln_g, ln_b, out);
}

// Round 5
// 305.494 us; speedup vs baseline: 3.7293x; 1.2095x over previous
//
#include <hip/hip_runtime.h>
#include <hip/hip_fp16.h>
#include <math.h>

#define NN   50000
#define EE   800000
#define HH   4
#define CC   32
#define DINN 128
#define ED   16
#define NEGS 0.2f
#define LNEPS 1e-5f
#define SCAN_NB ((NN + 255) / 256)   // 196

// Per-edge CSR record: exp(alpha) per head, a_e per head (half), src. 32 B.
struct __align__(16) Rec {
    float4  expa;
    __half2 ae01;
    __half2 ae23;
    int     src;
    int     pad;
};

struct __align__(8) Hp { __half2 a, b; };

// ---------------------------------------------------------------------------
// K2: h = x @ W_lin (N x 128) -> hbuf in fp16, plus a_src[n][h], a_dst[n][h]
// ---------------------------------------------------------------------------
__global__ __launch_bounds__(256, 2) void k_node(
        const float* __restrict__ x, const float* __restrict__ W_lin,
        const float* __restrict__ att_src, const float* __restrict__ att_dst,
        __half* __restrict__ hb, float* __restrict__ a_src, float* __restrict__ a_dst) {
    __shared__ float Wl[DINN * DINN];   // 64 KB
    __shared__ float xr[32 * DINN];     // 16 KB
    int t = threadIdx.x;

    {   // stage W (4096 float4)
        const float4* Wg = (const float4*)W_lin;
        float4* Ws = (float4*)Wl;
        #pragma unroll
        for (int i = 0; i < 16; ++i) Ws[t + 256 * i] = Wg[t + 256 * i];
    }
    int row0 = blockIdx.x * 32;
    {   // stage 32 rows of x (1024 float4)
        const float4* xg = (const float4*)x;
        float4* xs = (float4*)xr;
        #pragma unroll
        for (int i = 0; i < 4; ++i) {
            int idx = t + 256 * i;              // 0..1023
            int row = row0 + (idx >> 5);
            float4 v = make_float4(0.f, 0.f, 0.f, 0.f);
            if (row < NN) v = xg[(long)row * 32 + (idx & 31)];
            xs[idx] = v;
        }
    }
    __syncthreads();

    int cg = t & 31, rg = t >> 5;
    int j0 = cg * 4;
    float acc[4][4] = {};
    #pragma unroll 4
    for (int k = 0; k < DINN; ++k) {
        float4 w = *(const float4*)&Wl[k * DINN + j0];
        #pragma unroll
        for (int i = 0; i < 4; ++i) {
            float xv = xr[(rg * 4 + i) * DINN + k];
            acc[i][0] = fmaf(xv, w.x, acc[i][0]);
            acc[i][1] = fmaf(xv, w.y, acc[i][1]);
            acc[i][2] = fmaf(xv, w.z, acc[i][2]);
            acc[i][3] = fmaf(xv, w.w, acc[i][3]);
        }
    }

    int head = cg >> 3, c0 = (cg & 7) * 4;
    float4 as4 = *(const float4*)&att_src[head * CC + c0];
    float4 ad4 = *(const float4*)&att_dst[head * CC + c0];
    #pragma unroll
    for (int i = 0; i < 4; ++i) {
        int row = row0 + rg * 4 + i;
        if (row < NN) {
            Hp p;
            p.a = __floats2half2_rn(acc[i][0], acc[i][1]);
            p.b = __floats2half2_rn(acc[i][2], acc[i][3]);
            *(Hp*)&hb[(long)row * DINN + j0] = p;
        }
        float ps = acc[i][0] * as4.x + acc[i][1] * as4.y + acc[i][2] * as4.z + acc[i][3] * as4.w;
        float pd = acc[i][0] * ad4.x + acc[i][1] * ad4.y + acc[i][2] * ad4.z + acc[i][3] * ad4.w;
        #pragma unroll
        for (int mask = 1; mask < 8; mask <<= 1) {
            ps += __shfl_xor(ps, mask);
            pd += __shfl_xor(pd, mask);
        }
        if ((cg & 7) == 0 && row < NN) {
            a_src[row * 4 + head] = ps;
            a_dst[row * 4 + head] = pd;
        }
    }
}

// ---------------------------------------------------------------------------
// K3: in-degree count; atomic return value IS the CSR rank.
// ---------------------------------------------------------------------------
__global__ __launch_bounds__(256) void k_count(const int* __restrict__ ei,
                                               int* __restrict__ cnt,
                                               int* __restrict__ rank) {
    int e = blockIdx.x * 256 + threadIdx.x;
    if (e < EE) rank[e] = atomicAdd(cnt + ei[EE + e], 1);
}

// ---------------------------------------------------------------------------
// K4a: per-block sums of cnt (196 blocks x 256)
// ---------------------------------------------------------------------------
__global__ __launch_bounds__(256) void k_scanA(const int* __restrict__ cnt,
                                               int* __restrict__ partial) {
    int t = threadIdx.x, b = blockIdx.x;
    int i = b * 256 + t;
    int v = (i < NN) ? cnt[i] : 0;
    #pragma unroll
    for (int d = 1; d < 64; d <<= 1) v += __shfl_xor(v, d);
    __shared__ int wt[4];
    if ((t & 63) == 0) wt[t >> 6] = v;
    __syncthreads();
    if (t == 0) partial[b] = wt[0] + wt[1] + wt[2] + wt[3];
}

// ---------------------------------------------------------------------------
// K4b: exclusive scan of partial[196] -> poff; grand total -> row_start[NN];
//      folds v_edge precompute (v_edge[d][h] = sum_c W_edge[d][h*32+c]*att_edge[h][c]).
// ---------------------------------------------------------------------------
__global__ __launch_bounds__(256) void k_scanB(const int* __restrict__ partial,
                                               int* __restrict__ poff,
                                               int* __restrict__ row_start,
                                               const float* __restrict__ W_edge,
                                               const float* __restrict__ att_edge,
                                               float* __restrict__ v_edge) {
    int t = threadIdx.x;
    if (t < ED * HH) {
        int d = t >> 2, h = t & 3;
        float s = 0.f;
        for (int c = 0; c < CC; ++c)
            s += W_edge[d * (HH * CC) + h * CC + c] * att_edge[h * CC + c];
        v_edge[t] = s;
    }
    int lane = t & 63, w = t >> 6;
    int v = (t < SCAN_NB) ? partial[t] : 0;
    int sv = v;
    #pragma unroll
    for (int d = 1; d < 64; d <<= 1) {
        int o = __shfl_up(sv, d);
        if (lane >= d) sv += o;
    }
    __shared__ int wt[4];
    if (lane == 63) wt[w] = sv;
    __syncthreads();
    int base = 0;
    for (int j = 0; j < w; ++j) base += wt[j];
    if (t < SCAN_NB) poff[t] = base + sv - v;  // exclusive
    if (t == 255) row_start[NN] = wt[0] + wt[1] + wt[2] + wt[3];
}

// ---------------------------------------------------------------------------
// K4c: local exclusive scan per block + block offset -> row_start (coalesced)
// ---------------------------------------------------------------------------
__global__ __launch_bounds__(256) void k_scanC(const int* __restrict__ cnt,
                                               const int* __restrict__ poff,
                                               int* __restrict__ row_start) {
    int t = threadIdx.x, b = blockIdx.x;
    int i = b * 256 + t;
    int v = (i < NN) ? cnt[i] : 0;
    int lane = t & 63, w = t >> 6;
    int sv = v;
    #pragma unroll
    for (int d = 1; d < 64; d <<= 1) {
        int o = __shfl_up(sv, d);
        if (lane >= d) sv += o;
    }
    __shared__ int wt[4];
    if (lane == 63) wt[w] = sv;
    __syncthreads();
    int base = 0;
    for (int j = 0; j < w; ++j) base += wt[j];
    if (i < NN) row_start[i] = poff[b] + base + sv - v;
}

// ---------------------------------------------------------------------------
// K5: per edge: ea = relu(edge_attr@W_ep+b), a_e = ea.v_edge,
//     alpha = leaky(a_src[src]+a_dst[dst]+a_e).
//     Store ONE 32B record at row_start[dst]+rank[e] (atomic-free).
// ---------------------------------------------------------------------------
__global__ __launch_bounds__(256) void k_edge2(
        const int* __restrict__ ei, const float* __restrict__ edge_attr,
        const float* __restrict__ W_ep, const float* __restrict__ b_ep,
        const float* __restrict__ v_edge,
        const float* __restrict__ a_src, const float* __restrict__ a_dst,
        const int* __restrict__ row_start, const int* __restrict__ rank,
        Rec* __restrict__ rec) {
    __shared__ float Wl[ED * ED];
    __shared__ float bl[ED];
    __shared__ float vl[ED * 4];
    int t = threadIdx.x;
    if (t < ED * ED) Wl[t] = W_ep[t];
    if (t < ED) bl[t] = b_ep[t];
    if (t < ED * 4) vl[t] = v_edge[t];
    __syncthreads();

    int e = blockIdx.x * 256 + t;
    if (e >= EE) return;

    float a[ED];
    const float4* ap = (const float4*)(edge_attr + (long)e * ED);
    float4 a0 = ap[0], a1 = ap[1], a2 = ap[2], a3 = ap[3];
    a[0]=a0.x; a[1]=a0.y; a[2]=a0.z; a[3]=a0.w;
    a[4]=a1.x; a[5]=a1.y; a[6]=a1.z; a[7]=a1.w;
    a[8]=a2.x; a[9]=a2.y; a[10]=a2.z; a[11]=a2.w;
    a[12]=a3.x; a[13]=a3.y; a[14]=a3.z; a[15]=a3.w;

    float r[ED];
    #pragma unroll
    for (int j = 0; j < ED; ++j) r[j] = bl[j];
    #pragma unroll
    for (int d = 0; d < ED; ++d) {
        float av = a[d];
        #pragma unroll
        for (int j = 0; j < ED; ++j) r[j] = fmaf(av, Wl[d * ED + j], r[j]);
    }

    float ae0 = 0.f, ae1 = 0.f, ae2 = 0.f, ae3 = 0.f;
    #pragma unroll
    for (int d = 0; d < ED; ++d) {
        float rd = fmaxf(r[d], 0.f);
        ae0 = fmaf(rd, vl[d * 4 + 0], ae0);
        ae1 = fmaf(rd, vl[d * 4 + 1], ae1);
        ae2 = fmaf(rd, vl[d * 4 + 2], ae2);
        ae3 = fmaf(rd, vl[d * 4 + 3], ae3);
    }

    int src = ei[e];
    int dst = ei[EE + e];
    float4 s4 = *(const float4*)&a_src[src * 4];
    float4 d4 = *(const float4*)&a_dst[dst * 4];
    float v0 = s4.x + d4.x + ae0;
    float v1 = s4.y + d4.y + ae1;
    float v2 = s4.z + d4.z + ae2;
    float v3 = s4.w + d4.w + ae3;
    v0 = (v0 >= 0.f) ? v0 : NEGS * v0;
    v1 = (v1 >= 0.f) ? v1 : NEGS * v1;
    v2 = (v2 >= 0.f) ? v2 : NEGS * v2;
    v3 = (v3 >= 0.f) ? v3 : NEGS * v3;

    Rec rc;
    rc.expa = make_float4(__expf(v0), __expf(v1), __expf(v2), __expf(v3));
    rc.ae01 = __floats2half2_rn(ae0, ae1);
    rc.ae23 = __floats2half2_rn(ae2, ae3);
    rc.src  = src;
    rc.pad  = 0;
    rec[row_start[dst] + rank[e]] = rc;
}

// ---------------------------------------------------------------------------
// K6: one wave per node, single pass (per-lane complete softmax sums since
// every lane walks all edges). 4-wide unroll for gather ILP.
// ---------------------------------------------------------------------------
__global__ __launch_bounds__(256) void k_aggregate(
        const float* __restrict__ x, const __half2* __restrict__ hb,
        const float* __restrict__ a_src, const float* __restrict__ a_dst,
        const int* __restrict__ row_start, const Rec* __restrict__ rec,
        const float* __restrict__ bias, const float* __restrict__ ln_g,
        const float* __restrict__ ln_b, float* __restrict__ out) {
    int t = threadIdx.x;
    int wave = t >> 6, lane = t & 63;
    int n = blockIdx.x * 4 + wave;
    if (n >= NN) return;

    int start = row_start[n];
    int deg   = row_start[n + 1] - start;

    bool h1 = (lane & 32) != 0;   // head >= 2
    bool h0 = (lane & 16) != 0;   // head odd
    float accx = 0.f, accy = 0.f, s_own = 0.f, aes_own = 0.f;

    auto doEdge = [&](const Rec& r, __half2 hv) {
        float4 e4 = r.expa;
        float2 ef = h1 ? make_float2(e4.z, e4.w) : make_float2(e4.x, e4.y);
        float w = h0 ? ef.y : ef.x;
        float2 aef = __half22float2(h1 ? r.ae23 : r.ae01);
        aes_own += h0 ? aef.y : aef.x;
        s_own += w;
        float2 hf = __half22float2(hv);
        accx = fmaf(w, hf.x, accx);
        accy = fmaf(w, hf.y, accy);
    };

    const Rec* rp = rec + start;
    int k = 0;
    for (; k + 4 <= deg; k += 4) {
        Rec r0 = rp[k], r1 = rp[k + 1], r2 = rp[k + 2], r3 = rp[k + 3];
        __half2 v0 = hb[(long)r0.src * 64 + lane];
        __half2 v1 = hb[(long)r1.src * 64 + lane];
        __half2 v2 = hb[(long)r2.src * 64 + lane];
        __half2 v3 = hb[(long)r3.src * 64 + lane];
        doEdge(r0, v0); doEdge(r1, v1); doEdge(r2, v2); doEdge(r3, v3);
    }
    for (; k < deg; ++k) {
        Rec r = rp[k];
        doEdge(r, hb[(long)r.src * 64 + lane]);
    }

    // ---- self-loop from mean a_e ----
    int head = lane >> 4;
    float inv_deg = 1.0f / fmaxf((float)deg, 1.0f);
    float v = a_src[n * 4 + head] + a_dst[n * 4 + head] + aes_own * inv_deg;
    v = (v >= 0.f) ? v : NEGS * v;
    float w0 = __expf(v);
    s_own += w0;
    float2 hn = __half22float2(hb[(long)n * 64 + lane]);
    accx = fmaf(w0, hn.x, accx);
    accy = fmaf(w0, hn.y, accy);
    float is = 1.0f / s_own;
    accx *= is; accy *= is;

    // ---- bias + residual + LayerNorm (channels c0, c0+1) ----
    int c0 = lane * 2;
    float2 b2 = *(const float2*)&bias[c0];
    float2 x2 = *(const float2*)&x[(long)n * DINN + c0];
    float oa = accx + b2.x + x2.x;
    float ob = accy + b2.y + x2.y;
    float sum = oa + ob, sumsq = oa * oa + ob * ob;
    #pragma unroll
    for (int d2 = 1; d2 < 64; d2 <<= 1) {
        sum   += __shfl_xor(sum, d2);
        sumsq += __shfl_xor(sumsq, d2);
    }
    float mu  = sum * (1.0f / DINN);
    float var = sumsq * (1.0f / DINN) - mu * mu;
    float rs  = rsqrtf(var + LNEPS);
    float2 g2  = *(const float2*)&ln_g[c0];
    float2 lb2 = *(const float2*)&ln_b[c0];
    float2 o2;
    o2.x = (oa - mu) * rs * g2.x + lb2.x;
    o2.y = (ob - mu) * rs * g2.y + lb2.y;
    *(float2*)&out[(long)n * DINN + c0] = o2;
}

// ---------------------------------------------------------------------------
extern "C" void kernel_launch(void* const* d_in, const int* in_sizes, int n_in,
                              void* d_out, int out_size, void* d_ws, size_t ws_size,
                              hipStream_t stream) {
    const float* x         = (const float*)d_in[0];
    const int*   ei        = (const int*)d_in[1];
    const float* edge_attr = (const float*)d_in[2];
    const float* W_ep      = (const float*)d_in[3];
    const float* b_ep      = (const float*)d_in[4];
    const float* W_lin     = (const float*)d_in[5];
    const float* W_edge    = (const float*)d_in[6];
    const float* att_src   = (const float*)d_in[7];
    const float* att_dst   = (const float*)d_in[8];
    const float* att_edge  = (const float*)d_in[9];
    const float* bias      = (const float*)d_in[10];
    const float* ln_g      = (const float*)d_in[11];
    const float* ln_b      = (const float*)d_in[12];
    float* out = (float*)d_out;

    char* ws = (char*)d_ws;
    size_t o = 0;
    auto take = [&](size_t bytes) -> char* {
        char* p = ws + o;
        o = (o + bytes + 255) & ~(size_t)255;
        return p;
    };
    __half* hbuf      = (__half*)take((size_t)NN * DINN * 2);  // 12.8 MB
    float*  a_src     = (float*)take((size_t)NN * 4 * 4);
    float*  a_dst     = (float*)take((size_t)NN * 4 * 4);
    float*  v_edge    = (float*)take((size_t)ED * 4 * 4);
    int*    cnt       = (int*)  take((size_t)NN * 4);          // zeroed
    int*    row_start = (int*)  take((size_t)(NN + 1) * 4);
    int*    rank      = (int*)  take((size_t)EE * 4);          // 3.2 MB
    int*    partial   = (int*)  take((size_t)SCAN_NB * 4);
    int*    poff      = (int*)  take((size_t)SCAN_NB * 4);
    Rec*    rec       = (Rec*)  take((size_t)EE * sizeof(Rec)); // 25.6 MB

    hipMemsetAsync(cnt, 0, (size_t)NN * 4, stream);

    k_node<<<(NN + 31) / 32, 256, 0, stream>>>(x, W_lin, att_src, att_dst,
                                               hbuf, a_src, a_dst);
    k_count<<<(EE + 255) / 256, 256, 0, stream>>>(ei, cnt, rank);
    k_scanA<<<SCAN_NB, 256, 0, stream>>>(cnt, partial);
    k_scanB<<<1, 256, 0, stream>>>(partial, poff, row_start, W_edge, att_edge, v_edge);
    k_scanC<<<SCAN_NB, 256, 0, stream>>>(cnt, poff, row_start);
    k_edge2<<<(EE + 255) / 256, 256, 0, stream>>>(ei, edge_attr, W_ep, b_ep, v_edge,
                                                  a_src, a_dst, row_start, rank, rec);
    k_aggregate<<<(NN + 3) / 4, 256, 0, stream>>>(x, (const __half2*)hbuf,
                                                  a_src, a_dst, row_start, rec,
                                                  bias, ln_g, ln_b, out);
}

// Round 6
// 293.761 us; speedup vs baseline: 3.8783x; 1.0399x over previous
//
#include <hip/hip_runtime.h>
#include <hip/hip_fp16.h>
#include <math.h>

#define NN   50000
#define EE   800000
#define HH   4
#define CC   32
#define DINN 128
#define ED   16
#define NEGS 0.2f
#define LNEPS 1e-5f
#define SCAN_NB ((NN + 255) / 256)   // 196

struct __align__(16) Hp4 { __half2 a, b, c, d; };

// ---------------------------------------------------------------------------
// K2: h = x @ W_lin (N x 128) -> hbuf fp16, plus a_src/a_dst.
// 64 rows/block, 256 thr, thread = 4 rows x 8 cols. x in LDS (pad 132,
// 2-way-conflict = free); W streamed from global (L2-hot, 16-lane broadcast).
// ---------------------------------------------------------------------------
__global__ __launch_bounds__(256, 3) void k_node(
        const float* __restrict__ x, const float* __restrict__ W_lin,
        const float* __restrict__ att_src, const float* __restrict__ att_dst,
        __half* __restrict__ hb, float* __restrict__ a_src, float* __restrict__ a_dst) {
    __shared__ float xr[64 * 132];      // 33.8 KB
    int t = threadIdx.x;
    int row0 = blockIdx.x * 64;

    // stage 64 rows of x (2048 float4)
    #pragma unroll
    for (int i = 0; i < 8; ++i) {
        int idx = t + 256 * i;          // 0..2047
        int r = idx >> 5, kq = idx & 31;
        int row = row0 + r;
        float4 v = make_float4(0.f, 0.f, 0.f, 0.f);
        if (row < NN) v = ((const float4*)x)[(long)row * 32 + kq];
        *(float4*)&xr[r * 132 + kq * 4] = v;
    }
    __syncthreads();

    int colg = t & 15, rowg = t >> 4;
    int c0 = colg * 8;
    const float* Wp = W_lin + c0;
    float acc[4][8] = {};

    #pragma unroll 2
    for (int k = 0; k < DINN; k += 2) {
        float4 wa0 = *(const float4*)&Wp[(long)k * DINN];
        float4 wb0 = *(const float4*)&Wp[(long)k * DINN + 4];
        float4 wa1 = *(const float4*)&Wp[(long)(k + 1) * DINN];
        float4 wb1 = *(const float4*)&Wp[(long)(k + 1) * DINN + 4];
        #pragma unroll
        for (int i = 0; i < 4; ++i) {
            float2 xv = *(const float2*)&xr[(rowg * 4 + i) * 132 + k];
            acc[i][0] = fmaf(xv.x, wa0.x, acc[i][0]);
            acc[i][1] = fmaf(xv.x, wa0.y, acc[i][1]);
            acc[i][2] = fmaf(xv.x, wa0.z, acc[i][2]);
            acc[i][3] = fmaf(xv.x, wa0.w, acc[i][3]);
            acc[i][4] = fmaf(xv.x, wb0.x, acc[i][4]);
            acc[i][5] = fmaf(xv.x, wb0.y, acc[i][5]);
            acc[i][6] = fmaf(xv.x, wb0.z, acc[i][6]);
            acc[i][7] = fmaf(xv.x, wb0.w, acc[i][7]);
            acc[i][0] = fmaf(xv.y, wa1.x, acc[i][0]);
            acc[i][1] = fmaf(xv.y, wa1.y, acc[i][1]);
            acc[i][2] = fmaf(xv.y, wa1.z, acc[i][2]);
            acc[i][3] = fmaf(xv.y, wa1.w, acc[i][3]);
            acc[i][4] = fmaf(xv.y, wb1.x, acc[i][4]);
            acc[i][5] = fmaf(xv.y, wb1.y, acc[i][5]);
            acc[i][6] = fmaf(xv.y, wb1.z, acc[i][6]);
            acc[i][7] = fmaf(xv.y, wb1.w, acc[i][7]);
        }
    }

    int head = colg >> 2;               // c0/32
    int cw = c0 & 31;                   // within-head col base
    float4 as0 = *(const float4*)&att_src[head * CC + cw];
    float4 as1 = *(const float4*)&att_src[head * CC + cw + 4];
    float4 ad0 = *(const float4*)&att_dst[head * CC + cw];
    float4 ad1 = *(const float4*)&att_dst[head * CC + cw + 4];
    #pragma unroll
    for (int i = 0; i < 4; ++i) {
        int row = row0 + rowg * 4 + i;
        if (row < NN) {
            Hp4 p;
            p.a = __floats2half2_rn(acc[i][0], acc[i][1]);
            p.b = __floats2half2_rn(acc[i][2], acc[i][3]);
            p.c = __floats2half2_rn(acc[i][4], acc[i][5]);
            p.d = __floats2half2_rn(acc[i][6], acc[i][7]);
            *(Hp4*)&hb[(long)row * DINN + c0] = p;
        }
        float ps = acc[i][0]*as0.x + acc[i][1]*as0.y + acc[i][2]*as0.z + acc[i][3]*as0.w
                 + acc[i][4]*as1.x + acc[i][5]*as1.y + acc[i][6]*as1.z + acc[i][7]*as1.w;
        float pd = acc[i][0]*ad0.x + acc[i][1]*ad0.y + acc[i][2]*ad0.z + acc[i][3]*ad0.w
                 + acc[i][4]*ad1.x + acc[i][5]*ad1.y + acc[i][6]*ad1.z + acc[i][7]*ad1.w;
        ps += __shfl_xor(ps, 1); ps += __shfl_xor(ps, 2);
        pd += __shfl_xor(pd, 1); pd += __shfl_xor(pd, 2);
        if ((colg & 3) == 0 && row < NN) {
            a_src[row * 4 + head] = ps;
            a_dst[row * 4 + head] = pd;
        }
    }
}

// ---------------------------------------------------------------------------
// K3: in-degree count; atomic return value IS the CSR rank.
// ---------------------------------------------------------------------------
__global__ __launch_bounds__(256) void k_count(const int* __restrict__ ei,
                                               int* __restrict__ cnt,
                                               int* __restrict__ rank) {
    int e = blockIdx.x * 256 + threadIdx.x;
    if (e < EE) rank[e] = atomicAdd(cnt + ei[EE + e], 1);
}

// ---------------------------------------------------------------------------
// K4a/b/c: hierarchical exclusive scan of cnt -> row_start
// ---------------------------------------------------------------------------
__global__ __launch_bounds__(256) void k_scanA(const int* __restrict__ cnt,
                                               int* __restrict__ partial) {
    int t = threadIdx.x, b = blockIdx.x;
    int i = b * 256 + t;
    int v = (i < NN) ? cnt[i] : 0;
    #pragma unroll
    for (int d = 1; d < 64; d <<= 1) v += __shfl_xor(v, d);
    __shared__ int wt[4];
    if ((t & 63) == 0) wt[t >> 6] = v;
    __syncthreads();
    if (t == 0) partial[b] = wt[0] + wt[1] + wt[2] + wt[3];
}

__global__ __launch_bounds__(256) void k_scanB(const int* __restrict__ partial,
                                               int* __restrict__ poff,
                                               int* __restrict__ row_start,
                                               const float* __restrict__ W_edge,
                                               const float* __restrict__ att_edge,
                                               float* __restrict__ v_edge) {
    int t = threadIdx.x;
    if (t < ED * HH) {
        int d = t >> 2, h = t & 3;
        float s = 0.f;
        for (int c = 0; c < CC; ++c)
            s += W_edge[d * (HH * CC) + h * CC + c] * att_edge[h * CC + c];
        v_edge[t] = s;
    }
    int lane = t & 63, w = t >> 6;
    int v = (t < SCAN_NB) ? partial[t] : 0;
    int sv = v;
    #pragma unroll
    for (int d = 1; d < 64; d <<= 1) {
        int o = __shfl_up(sv, d);
        if (lane >= d) sv += o;
    }
    __shared__ int wt[4];
    if (lane == 63) wt[w] = sv;
    __syncthreads();
    int base = 0;
    for (int j = 0; j < w; ++j) base += wt[j];
    if (t < SCAN_NB) poff[t] = base + sv - v;
    if (t == 255) row_start[NN] = wt[0] + wt[1] + wt[2] + wt[3];
}

__global__ __launch_bounds__(256) void k_scanC(const int* __restrict__ cnt,
                                               const int* __restrict__ poff,
                                               int* __restrict__ row_start) {
    int t = threadIdx.x, b = blockIdx.x;
    int i = b * 256 + t;
    int v = (i < NN) ? cnt[i] : 0;
    int lane = t & 63, w = t >> 6;
    int sv = v;
    #pragma unroll
    for (int d = 1; d < 64; d <<= 1) {
        int o = __shfl_up(sv, d);
        if (lane >= d) sv += o;
    }
    __shared__ int wt[4];
    if (lane == 63) wt[w] = sv;
    __syncthreads();
    int base = 0;
    for (int j = 0; j < w; ++j) base += wt[j];
    if (i < NN) row_start[i] = poff[b] + base + sv - v;
}

// ---------------------------------------------------------------------------
// K5: per edge: ea = relu(edge_attr@W_ep+b), a_e = ea.v_edge,
//     alpha = leaky(a_src[src]+a_dst[dst]+a_e).
//     Emit packed SoA: pk[pos*4+h] = half2(exp(alpha_h), a_e_h), src[pos].
// ---------------------------------------------------------------------------
__global__ __launch_bounds__(256) void k_edge2(
        const int* __restrict__ ei, const float* __restrict__ edge_attr,
        const float* __restrict__ W_ep, const float* __restrict__ b_ep,
        const float* __restrict__ v_edge,
        const float* __restrict__ a_src, const float* __restrict__ a_dst,
        const int* __restrict__ row_start, const int* __restrict__ rank,
        uint4* __restrict__ pk, int* __restrict__ csr_src) {
    __shared__ float Wl[ED * ED];
    __shared__ float bl[ED];
    __shared__ float vl[ED * 4];
    int t = threadIdx.x;
    if (t < ED * ED) Wl[t] = W_ep[t];
    if (t < ED) bl[t] = b_ep[t];
    if (t < ED * 4) vl[t] = v_edge[t];
    __syncthreads();

    int e = blockIdx.x * 256 + t;
    if (e >= EE) return;

    float a[ED];
    const float4* ap = (const float4*)(edge_attr + (long)e * ED);
    float4 a0 = ap[0], a1 = ap[1], a2 = ap[2], a3 = ap[3];
    a[0]=a0.x; a[1]=a0.y; a[2]=a0.z; a[3]=a0.w;
    a[4]=a1.x; a[5]=a1.y; a[6]=a1.z; a[7]=a1.w;
    a[8]=a2.x; a[9]=a2.y; a[10]=a2.z; a[11]=a2.w;
    a[12]=a3.x; a[13]=a3.y; a[14]=a3.z; a[15]=a3.w;

    float r[ED];
    #pragma unroll
    for (int j = 0; j < ED; ++j) r[j] = bl[j];
    #pragma unroll
    for (int d = 0; d < ED; ++d) {
        float av = a[d];
        #pragma unroll
        for (int j = 0; j < ED; ++j) r[j] = fmaf(av, Wl[d * ED + j], r[j]);
    }

    float ae0 = 0.f, ae1 = 0.f, ae2 = 0.f, ae3 = 0.f;
    #pragma unroll
    for (int d = 0; d < ED; ++d) {
        float rd = fmaxf(r[d], 0.f);
        ae0 = fmaf(rd, vl[d * 4 + 0], ae0);
        ae1 = fmaf(rd, vl[d * 4 + 1], ae1);
        ae2 = fmaf(rd, vl[d * 4 + 2], ae2);
        ae3 = fmaf(rd, vl[d * 4 + 3], ae3);
    }

    int src = ei[e];
    int dst = ei[EE + e];
    float4 s4 = *(const float4*)&a_src[src * 4];
    float4 d4 = *(const float4*)&a_dst[dst * 4];
    float v0 = s4.x + d4.x + ae0;
    float v1 = s4.y + d4.y + ae1;
    float v2 = s4.z + d4.z + ae2;
    float v3 = s4.w + d4.w + ae3;
    v0 = (v0 >= 0.f) ? v0 : NEGS * v0;
    v1 = (v1 >= 0.f) ? v1 : NEGS * v1;
    v2 = (v2 >= 0.f) ? v2 : NEGS * v2;
    v3 = (v3 >= 0.f) ? v3 : NEGS * v3;

    __half2 p0 = __floats2half2_rn(__expf(v0), ae0);
    __half2 p1 = __floats2half2_rn(__expf(v1), ae1);
    __half2 p2 = __floats2half2_rn(__expf(v2), ae2);
    __half2 p3 = __floats2half2_rn(__expf(v3), ae3);
    int pos = row_start[dst] + rank[e];
    pk[pos] = make_uint4(*(unsigned*)&p0, *(unsigned*)&p1,
                         *(unsigned*)&p2, *(unsigned*)&p3);
    csr_src[pos] = src;
}

// ---------------------------------------------------------------------------
// K6: one wave per node, single pass, 8-wide unrolled. Lane owns channels
// {2*lane, 2*lane+1}; head = lane>>4. Per edge per lane: 1 dword packed
// (exp|ae) + 1 dword src + 1 dword half2 gather.
// ---------------------------------------------------------------------------
__global__ __launch_bounds__(256) void k_aggregate(
        const float* __restrict__ x, const __half2* __restrict__ hb,
        const float* __restrict__ a_src, const float* __restrict__ a_dst,
        const int* __restrict__ row_start,
        const unsigned* __restrict__ pkh, const int* __restrict__ srcs,
        const float* __restrict__ bias, const float* __restrict__ ln_g,
        const float* __restrict__ ln_b, float* __restrict__ out) {
    int t = threadIdx.x;
    int wave = t >> 6, lane = t & 63;
    int n = blockIdx.x * 4 + wave;
    if (n >= NN) return;

    int start = row_start[n];
    int deg   = row_start[n + 1] - start;
    int head  = lane >> 4;

    float accx = 0.f, accy = 0.f, s_own = 0.f, aes_own = 0.f;
    const unsigned* pp = pkh + (size_t)start * 4 + head;
    const int* sp = srcs + start;

    int k = 0;
    for (; k + 8 <= deg; k += 8) {
        unsigned pv[8]; int sv[8];
        #pragma unroll
        for (int j = 0; j < 8; ++j) {
            pv[j] = pp[(size_t)(k + j) * 4];
            sv[j] = sp[k + j];
        }
        __half2 hv[8];
        #pragma unroll
        for (int j = 0; j < 8; ++j) hv[j] = hb[(long)sv[j] * 64 + lane];
        #pragma unroll
        for (int j = 0; j < 8; ++j) {
            float2 wf = __half22float2(*(__half2*)&pv[j]);
            s_own += wf.x;
            aes_own += wf.y;
            float2 hf = __half22float2(hv[j]);
            accx = fmaf(wf.x, hf.x, accx);
            accy = fmaf(wf.x, hf.y, accy);
        }
    }
    for (; k < deg; ++k) {
        unsigned p = pp[(size_t)k * 4];
        int src = sp[k];
        __half2 hv = hb[(long)src * 64 + lane];
        float2 wf = __half22float2(*(__half2*)&p);
        s_own += wf.x;
        aes_own += wf.y;
        float2 hf = __half22float2(hv);
        accx = fmaf(wf.x, hf.x, accx);
        accy = fmaf(wf.x, hf.y, accy);
    }

    // ---- self-loop from mean a_e ----
    float inv_deg = 1.0f / fmaxf((float)deg, 1.0f);
    float v = a_src[n * 4 + head] + a_dst[n * 4 + head] + aes_own * inv_deg;
    v = (v >= 0.f) ? v : NEGS * v;
    float w0 = __expf(v);
    s_own += w0;
    float2 hn = __half22float2(hb[(long)n * 64 + lane]);
    accx = fmaf(w0, hn.x, accx);
    accy = fmaf(w0, hn.y, accy);
    float is = 1.0f / s_own;
    accx *= is; accy *= is;

    // ---- bias + residual + LayerNorm ----
    int c0 = lane * 2;
    float2 b2 = *(const float2*)&bias[c0];
    float2 x2 = *(const float2*)&x[(long)n * DINN + c0];
    float oa = accx + b2.x + x2.x;
    float ob = accy + b2.y + x2.y;
    float sum = oa + ob, sumsq = oa * oa + ob * ob;
    #pragma unroll
    for (int d2 = 1; d2 < 64; d2 <<= 1) {
        sum   += __shfl_xor(sum, d2);
        sumsq += __shfl_xor(sumsq, d2);
    }
    float mu  = sum * (1.0f / DINN);
    float var = sumsq * (1.0f / DINN) - mu * mu;
    float rs  = rsqrtf(var + LNEPS);
    float2 g2  = *(const float2*)&ln_g[c0];
    float2 lb2 = *(const float2*)&ln_b[c0];
    float2 o2;
    o2.x = (oa - mu) * rs * g2.x + lb2.x;
    o2.y = (ob - mu) * rs * g2.y + lb2.y;
    *(float2*)&out[(long)n * DINN + c0] = o2;
}

// ---------------------------------------------------------------------------
extern "C" void kernel_launch(void* const* d_in, const int* in_sizes, int n_in,
                              void* d_out, int out_size, void* d_ws, size_t ws_size,
                              hipStream_t stream) {
    const float* x         = (const float*)d_in[0];
    const int*   ei        = (const int*)d_in[1];
    const float* edge_attr = (const float*)d_in[2];
    const float* W_ep      = (const float*)d_in[3];
    const float* b_ep      = (const float*)d_in[4];
    const float* W_lin     = (const float*)d_in[5];
    const float* W_edge    = (const float*)d_in[6];
    const float* att_src   = (const float*)d_in[7];
    const float* att_dst   = (const float*)d_in[8];
    const float* att_edge  = (const float*)d_in[9];
    const float* bias      = (const float*)d_in[10];
    const float* ln_g      = (const float*)d_in[11];
    const float* ln_b      = (const float*)d_in[12];
    float* out = (float*)d_out;

    char* ws = (char*)d_ws;
    size_t o = 0;
    auto take = [&](size_t bytes) -> char* {
        char* p = ws + o;
        o = (o + bytes + 255) & ~(size_t)255;
        return p;
    };
    __half* hbuf      = (__half*)take((size_t)NN * DINN * 2);  // 12.8 MB
    float*  a_src     = (float*)take((size_t)NN * 4 * 4);
    float*  a_dst     = (float*)take((size_t)NN * 4 * 4);
    float*  v_edge    = (float*)take((size_t)ED * 4 * 4);
    int*    cnt       = (int*)  take((size_t)NN * 4);          // zeroed
    int*    row_start = (int*)  take((size_t)(NN + 1) * 4);
    int*    rank      = (int*)  take((size_t)EE * 4);          // 3.2 MB
    int*    partial   = (int*)  take((size_t)SCAN_NB * 4);
    int*    poff      = (int*)  take((size_t)SCAN_NB * 4);
    uint4*  pk        = (uint4*)take((size_t)EE * 16);         // 12.8 MB
    int*    csr_src   = (int*)  take((size_t)EE * 4);          // 3.2 MB

    hipMemsetAsync(cnt, 0, (size_t)NN * 4, stream);

    k_node<<<(NN + 63) / 64, 256, 0, stream>>>(x, W_lin, att_src, att_dst,
                                               hbuf, a_src, a_dst);
    k_count<<<(EE + 255) / 256, 256, 0, stream>>>(ei, cnt, rank);
    k_scanA<<<SCAN_NB, 256, 0, stream>>>(cnt, partial);
    k_scanB<<<1, 256, 0, stream>>>(partial, poff, row_start, W_edge, att_edge, v_edge);
    k_scanC<<<SCAN_NB, 256, 0, stream>>>(cnt, poff, row_start);
    k_edge2<<<(EE + 255) / 256, 256, 0, stream>>>(ei, edge_attr, W_ep, b_ep, v_edge,
                                                  a_src, a_dst, row_start, rank,
                                                  pk, csr_src);
    k_aggregate<<<(NN + 3) / 4, 256, 0, stream>>>(x, (const __half2*)hbuf,
                                                  a_src, a_dst, row_start,
                                                  (const unsigned*)pk, csr_src,
                                                  bias, ln_g, ln_b, out);
}

// Round 7
// 284.462 us; speedup vs baseline: 4.0050x; 1.0327x over previous
//
#include <hip/hip_runtime.h>
#include <hip/hip_fp16.h>
#include <math.h>

#define NN   50000
#define EE   800000
#define HH   4
#define CC   32
#define DINN 128
#define ED   16
#define NEGS 0.2f
#define LNEPS 1e-5f
#define SCAN_NB ((NN + 255) / 256)   // 196

struct __align__(16) Hp4 { __half2 a, b, c, d; };

// ---------------------------------------------------------------------------
// K2: h = x @ W_lin (N x 128) -> hbuf fp16, plus a_src/a_dst.
// 64 rows/block, thread = 4 rows x 8 cols; x in LDS (pad 132), W from L2.
// ---------------------------------------------------------------------------
__global__ __launch_bounds__(256, 3) void k_node(
        const float* __restrict__ x, const float* __restrict__ W_lin,
        const float* __restrict__ att_src, const float* __restrict__ att_dst,
        __half* __restrict__ hb, float* __restrict__ a_src, float* __restrict__ a_dst) {
    __shared__ float xr[64 * 132];      // 33.8 KB
    int t = threadIdx.x;
    int row0 = blockIdx.x * 64;

    #pragma unroll
    for (int i = 0; i < 8; ++i) {
        int idx = t + 256 * i;          // 0..2047
        int r = idx >> 5, kq = idx & 31;
        int row = row0 + r;
        float4 v = make_float4(0.f, 0.f, 0.f, 0.f);
        if (row < NN) v = ((const float4*)x)[(long)row * 32 + kq];
        *(float4*)&xr[r * 132 + kq * 4] = v;
    }
    __syncthreads();

    int colg = t & 15, rowg = t >> 4;
    int c0 = colg * 8;
    const float* Wp = W_lin + c0;
    float acc[4][8] = {};

    #pragma unroll 2
    for (int k = 0; k < DINN; k += 2) {
        float4 wa0 = *(const float4*)&Wp[(long)k * DINN];
        float4 wb0 = *(const float4*)&Wp[(long)k * DINN + 4];
        float4 wa1 = *(const float4*)&Wp[(long)(k + 1) * DINN];
        float4 wb1 = *(const float4*)&Wp[(long)(k + 1) * DINN + 4];
        #pragma unroll
        for (int i = 0; i < 4; ++i) {
            float2 xv = *(const float2*)&xr[(rowg * 4 + i) * 132 + k];
            acc[i][0] = fmaf(xv.x, wa0.x, acc[i][0]);
            acc[i][1] = fmaf(xv.x, wa0.y, acc[i][1]);
            acc[i][2] = fmaf(xv.x, wa0.z, acc[i][2]);
            acc[i][3] = fmaf(xv.x, wa0.w, acc[i][3]);
            acc[i][4] = fmaf(xv.x, wb0.x, acc[i][4]);
            acc[i][5] = fmaf(xv.x, wb0.y, acc[i][5]);
            acc[i][6] = fmaf(xv.x, wb0.z, acc[i][6]);
            acc[i][7] = fmaf(xv.x, wb0.w, acc[i][7]);
            acc[i][0] = fmaf(xv.y, wa1.x, acc[i][0]);
            acc[i][1] = fmaf(xv.y, wa1.y, acc[i][1]);
            acc[i][2] = fmaf(xv.y, wa1.z, acc[i][2]);
            acc[i][3] = fmaf(xv.y, wa1.w, acc[i][3]);
            acc[i][4] = fmaf(xv.y, wb1.x, acc[i][4]);
            acc[i][5] = fmaf(xv.y, wb1.y, acc[i][5]);
            acc[i][6] = fmaf(xv.y, wb1.z, acc[i][6]);
            acc[i][7] = fmaf(xv.y, wb1.w, acc[i][7]);
        }
    }

    int head = colg >> 2;
    int cw = c0 & 31;
    float4 as0 = *(const float4*)&att_src[head * CC + cw];
    float4 as1 = *(const float4*)&att_src[head * CC + cw + 4];
    float4 ad0 = *(const float4*)&att_dst[head * CC + cw];
    float4 ad1 = *(const float4*)&att_dst[head * CC + cw + 4];
    #pragma unroll
    for (int i = 0; i < 4; ++i) {
        int row = row0 + rowg * 4 + i;
        if (row < NN) {
            Hp4 p;
            p.a = __floats2half2_rn(acc[i][0], acc[i][1]);
            p.b = __floats2half2_rn(acc[i][2], acc[i][3]);
            p.c = __floats2half2_rn(acc[i][4], acc[i][5]);
            p.d = __floats2half2_rn(acc[i][6], acc[i][7]);
            *(Hp4*)&hb[(long)row * DINN + c0] = p;
        }
        float ps = acc[i][0]*as0.x + acc[i][1]*as0.y + acc[i][2]*as0.z + acc[i][3]*as0.w
                 + acc[i][4]*as1.x + acc[i][5]*as1.y + acc[i][6]*as1.z + acc[i][7]*as1.w;
        float pd = acc[i][0]*ad0.x + acc[i][1]*ad0.y + acc[i][2]*ad0.z + acc[i][3]*ad0.w
                 + acc[i][4]*ad1.x + acc[i][5]*ad1.y + acc[i][6]*ad1.z + acc[i][7]*ad1.w;
        ps += __shfl_xor(ps, 1); ps += __shfl_xor(ps, 2);
        pd += __shfl_xor(pd, 1); pd += __shfl_xor(pd, 2);
        if ((colg & 3) == 0 && row < NN) {
            a_src[row * 4 + head] = ps;
            a_dst[row * 4 + head] = pd;
        }
    }
}

// ---------------------------------------------------------------------------
// K3 (edgeA): per edge (needs a_src/a_dst, so runs after k_node):
//   ea = relu(edge_attr@W_ep+b), a_e = ea.v_edge (v_edge built in LDS),
//   alpha = leaky(a_src[src]+a_dst[dst]+a_e),
//   payload[e] = {half2(exp(alpha_h), a_e_h)}x4 (coalesced, edge order),
//   rank[e] = atomicAdd(cnt+dst, 1).
// All the compute/gathers hide under the rank-atomic latency.
// ---------------------------------------------------------------------------
__global__ __launch_bounds__(256) void k_edgeA(
        const int* __restrict__ ei, const float* __restrict__ edge_attr,
        const float* __restrict__ W_ep, const float* __restrict__ b_ep,
        const float* __restrict__ W_edge, const float* __restrict__ att_edge,
        const float* __restrict__ a_src, const float* __restrict__ a_dst,
        int* __restrict__ cnt, int* __restrict__ rank,
        uint4* __restrict__ payload) {
    __shared__ float Wl[ED * ED];
    __shared__ float bl[ED];
    __shared__ float vl[ED * 4];
    int t = threadIdx.x;
    if (t < ED * ED) Wl[t] = W_ep[t];
    if (t < ED) bl[t] = b_ep[t];
    if (t >= 192 && t < 192 + 64) {      // 64 threads build v_edge
        int q = t - 192;
        int d = q >> 2, h = q & 3;
        float s = 0.f;
        #pragma unroll 8
        for (int c = 0; c < CC; ++c)
            s += W_edge[d * (HH * CC) + h * CC + c] * att_edge[h * CC + c];
        vl[q] = s;
    }
    __syncthreads();

    int e = blockIdx.x * 256 + t;
    if (e >= EE) return;

    int src = ei[e];
    int dst = ei[EE + e];

    float a[ED];
    const float4* ap = (const float4*)(edge_attr + (long)e * ED);
    float4 a0 = ap[0], a1 = ap[1], a2 = ap[2], a3 = ap[3];
    a[0]=a0.x; a[1]=a0.y; a[2]=a0.z; a[3]=a0.w;
    a[4]=a1.x; a[5]=a1.y; a[6]=a1.z; a[7]=a1.w;
    a[8]=a2.x; a[9]=a2.y; a[10]=a2.z; a[11]=a2.w;
    a[12]=a3.x; a[13]=a3.y; a[14]=a3.z; a[15]=a3.w;

    float4 s4 = *(const float4*)&a_src[src * 4];
    float4 d4 = *(const float4*)&a_dst[dst * 4];

    float r[ED];
    #pragma unroll
    for (int j = 0; j < ED; ++j) r[j] = bl[j];
    #pragma unroll
    for (int d = 0; d < ED; ++d) {
        float av = a[d];
        #pragma unroll
        for (int j = 0; j < ED; ++j) r[j] = fmaf(av, Wl[d * ED + j], r[j]);
    }

    float ae0 = 0.f, ae1 = 0.f, ae2 = 0.f, ae3 = 0.f;
    #pragma unroll
    for (int d = 0; d < ED; ++d) {
        float rd = fmaxf(r[d], 0.f);
        ae0 = fmaf(rd, vl[d * 4 + 0], ae0);
        ae1 = fmaf(rd, vl[d * 4 + 1], ae1);
        ae2 = fmaf(rd, vl[d * 4 + 2], ae2);
        ae3 = fmaf(rd, vl[d * 4 + 3], ae3);
    }

    float v0 = s4.x + d4.x + ae0;
    float v1 = s4.y + d4.y + ae1;
    float v2 = s4.z + d4.z + ae2;
    float v3 = s4.w + d4.w + ae3;
    v0 = (v0 >= 0.f) ? v0 : NEGS * v0;
    v1 = (v1 >= 0.f) ? v1 : NEGS * v1;
    v2 = (v2 >= 0.f) ? v2 : NEGS * v2;
    v3 = (v3 >= 0.f) ? v3 : NEGS * v3;

    __half2 p0 = __floats2half2_rn(__expf(v0), ae0);
    __half2 p1 = __floats2half2_rn(__expf(v1), ae1);
    __half2 p2 = __floats2half2_rn(__expf(v2), ae2);
    __half2 p3 = __floats2half2_rn(__expf(v3), ae3);
    payload[e] = make_uint4(*(unsigned*)&p0, *(unsigned*)&p1,
                            *(unsigned*)&p2, *(unsigned*)&p3);
    rank[e] = atomicAdd(cnt + dst, 1);
}

// ---------------------------------------------------------------------------
// K4a/b/c: hierarchical exclusive scan of cnt -> row_start
// ---------------------------------------------------------------------------
__global__ __launch_bounds__(256) void k_scanA(const int* __restrict__ cnt,
                                               int* __restrict__ partial) {
    int t = threadIdx.x, b = blockIdx.x;
    int i = b * 256 + t;
    int v = (i < NN) ? cnt[i] : 0;
    #pragma unroll
    for (int d = 1; d < 64; d <<= 1) v += __shfl_xor(v, d);
    __shared__ int wt[4];
    if ((t & 63) == 0) wt[t >> 6] = v;
    __syncthreads();
    if (t == 0) partial[b] = wt[0] + wt[1] + wt[2] + wt[3];
}

__global__ __launch_bounds__(256) void k_scanB(const int* __restrict__ partial,
                                               int* __restrict__ poff,
                                               int* __restrict__ row_start) {
    int t = threadIdx.x;
    int lane = t & 63, w = t >> 6;
    int v = (t < SCAN_NB) ? partial[t] : 0;
    int sv = v;
    #pragma unroll
    for (int d = 1; d < 64; d <<= 1) {
        int o = __shfl_up(sv, d);
        if (lane >= d) sv += o;
    }
    __shared__ int wt[4];
    if (lane == 63) wt[w] = sv;
    __syncthreads();
    int base = 0;
    for (int j = 0; j < w; ++j) base += wt[j];
    if (t < SCAN_NB) poff[t] = base + sv - v;
    if (t == 255) row_start[NN] = wt[0] + wt[1] + wt[2] + wt[3];
}

__global__ __launch_bounds__(256) void k_scanC(const int* __restrict__ cnt,
                                               const int* __restrict__ poff,
                                               int* __restrict__ row_start) {
    int t = threadIdx.x, b = blockIdx.x;
    int i = b * 256 + t;
    int v = (i < NN) ? cnt[i] : 0;
    int lane = t & 63, w = t >> 6;
    int sv = v;
    #pragma unroll
    for (int d = 1; d < 64; d <<= 1) {
        int o = __shfl_up(sv, d);
        if (lane >= d) sv += o;
    }
    __shared__ int wt[4];
    if (lane == 63) wt[w] = sv;
    __syncthreads();
    int base = 0;
    for (int j = 0; j < w; ++j) base += wt[j];
    if (i < NN) row_start[i] = poff[b] + base + sv - v;
}

// ---------------------------------------------------------------------------
// K5 (edgeB): pure permute into CSR order. 4 edges/thread, vectorized reads,
// one row_start gather + 20B scatter per edge. Minimal chain, deep batching.
// ---------------------------------------------------------------------------
__global__ __launch_bounds__(256) void k_edgeB(
        const int* __restrict__ ei, const uint4* __restrict__ payload,
        const int* __restrict__ rank, const int* __restrict__ row_start,
        uint4* __restrict__ pk, int* __restrict__ csr_src) {
    int base = (blockIdx.x * 256 + threadIdx.x) * 4;
    if (base + 3 < EE) {
        int4 s4 = *(const int4*)(ei + base);
        int4 d4 = *(const int4*)(ei + EE + base);
        int4 r4 = *(const int4*)(rank + base);
        uint4 p0 = payload[base], p1 = payload[base + 1];
        uint4 p2 = payload[base + 2], p3 = payload[base + 3];
        int q0 = row_start[d4.x] + r4.x;
        int q1 = row_start[d4.y] + r4.y;
        int q2 = row_start[d4.z] + r4.z;
        int q3 = row_start[d4.w] + r4.w;
        pk[q0] = p0; pk[q1] = p1; pk[q2] = p2; pk[q3] = p3;
        csr_src[q0] = s4.x; csr_src[q1] = s4.y;
        csr_src[q2] = s4.z; csr_src[q3] = s4.w;
    } else {
        for (int e = base; e < EE; ++e) {
            int q = row_start[ei[EE + e]] + rank[e];
            pk[q] = payload[e];
            csr_src[q] = ei[e];
        }
    }
}

// ---------------------------------------------------------------------------
// K6: one wave per node, single pass, 8-wide unrolled. Lane owns channels
// {2*lane, 2*lane+1}; head = lane>>4.
// ---------------------------------------------------------------------------
__global__ __launch_bounds__(256) void k_aggregate(
        const float* __restrict__ x, const __half2* __restrict__ hb,
        const float* __restrict__ a_src, const float* __restrict__ a_dst,
        const int* __restrict__ row_start,
        const unsigned* __restrict__ pkh, const int* __restrict__ srcs,
        const float* __restrict__ bias, const float* __restrict__ ln_g,
        const float* __restrict__ ln_b, float* __restrict__ out) {
    int t = threadIdx.x;
    int wave = t >> 6, lane = t & 63;
    int n = blockIdx.x * 4 + wave;
    if (n >= NN) return;

    int start = row_start[n];
    int deg   = row_start[n + 1] - start;
    int head  = lane >> 4;

    float accx = 0.f, accy = 0.f, s_own = 0.f, aes_own = 0.f;
    const unsigned* pp = pkh + (size_t)start * 4 + head;
    const int* sp = srcs + start;

    int k = 0;
    for (; k + 8 <= deg; k += 8) {
        unsigned pv[8]; int sv[8];
        #pragma unroll
        for (int j = 0; j < 8; ++j) {
            pv[j] = pp[(size_t)(k + j) * 4];
            sv[j] = sp[k + j];
        }
        __half2 hv[8];
        #pragma unroll
        for (int j = 0; j < 8; ++j) hv[j] = hb[(long)sv[j] * 64 + lane];
        #pragma unroll
        for (int j = 0; j < 8; ++j) {
            float2 wf = __half22float2(*(__half2*)&pv[j]);
            s_own += wf.x;
            aes_own += wf.y;
            float2 hf = __half22float2(hv[j]);
            accx = fmaf(wf.x, hf.x, accx);
            accy = fmaf(wf.x, hf.y, accy);
        }
    }
    for (; k < deg; ++k) {
        unsigned p = pp[(size_t)k * 4];
        int src = sp[k];
        __half2 hv = hb[(long)src * 64 + lane];
        float2 wf = __half22float2(*(__half2*)&p);
        s_own += wf.x;
        aes_own += wf.y;
        float2 hf = __half22float2(hv);
        accx = fmaf(wf.x, hf.x, accx);
        accy = fmaf(wf.x, hf.y, accy);
    }

    float inv_deg = 1.0f / fmaxf((float)deg, 1.0f);
    float v = a_src[n * 4 + head] + a_dst[n * 4 + head] + aes_own * inv_deg;
    v = (v >= 0.f) ? v : NEGS * v;
    float w0 = __expf(v);
    s_own += w0;
    float2 hn = __half22float2(hb[(long)n * 64 + lane]);
    accx = fmaf(w0, hn.x, accx);
    accy = fmaf(w0, hn.y, accy);
    float is = 1.0f / s_own;
    accx *= is; accy *= is;

    int c0 = lane * 2;
    float2 b2 = *(const float2*)&bias[c0];
    float2 x2 = *(const float2*)&x[(long)n * DINN + c0];
    float oa = accx + b2.x + x2.x;
    float ob = accy + b2.y + x2.y;
    float sum = oa + ob, sumsq = oa * oa + ob * ob;
    #pragma unroll
    for (int d2 = 1; d2 < 64; d2 <<= 1) {
        sum   += __shfl_xor(sum, d2);
        sumsq += __shfl_xor(sumsq, d2);
    }
    float mu  = sum * (1.0f / DINN);
    float var = sumsq * (1.0f / DINN) - mu * mu;
    float rs  = rsqrtf(var + LNEPS);
    float2 g2  = *(const float2*)&ln_g[c0];
    float2 lb2 = *(const float2*)&ln_b[c0];
    float2 o2;
    o2.x = (oa - mu) * rs * g2.x + lb2.x;
    o2.y = (ob - mu) * rs * g2.y + lb2.y;
    *(float2*)&out[(long)n * DINN + c0] = o2;
}

// ---------------------------------------------------------------------------
extern "C" void kernel_launch(void* const* d_in, const int* in_sizes, int n_in,
                              void* d_out, int out_size, void* d_ws, size_t ws_size,
                              hipStream_t stream) {
    const float* x         = (const float*)d_in[0];
    const int*   ei        = (const int*)d_in[1];
    const float* edge_attr = (const float*)d_in[2];
    const float* W_ep      = (const float*)d_in[3];
    const float* b_ep      = (const float*)d_in[4];
    const float* W_lin     = (const float*)d_in[5];
    const float* W_edge    = (const float*)d_in[6];
    const float* att_src   = (const float*)d_in[7];
    const float* att_dst   = (const float*)d_in[8];
    const float* att_edge  = (const float*)d_in[9];
    const float* bias      = (const float*)d_in[10];
    const float* ln_g      = (const float*)d_in[11];
    const float* ln_b      = (const float*)d_in[12];
    float* out = (float*)d_out;

    char* ws = (char*)d_ws;
    size_t o = 0;
    auto take = [&](size_t bytes) -> char* {
        char* p = ws + o;
        o = (o + bytes + 255) & ~(size_t)255;
        return p;
    };
    __half* hbuf      = (__half*)take((size_t)NN * DINN * 2);   // 12.8 MB
    float*  a_src     = (float*)take((size_t)NN * 4 * 4);
    float*  a_dst     = (float*)take((size_t)NN * 4 * 4);
    int*    cnt       = (int*)  take((size_t)NN * 4);           // zeroed
    int*    row_start = (int*)  take((size_t)(NN + 1) * 4);
    int*    rank      = (int*)  take((size_t)EE * 4);           // 3.2 MB
    int*    partial   = (int*)  take((size_t)SCAN_NB * 4);
    int*    poff      = (int*)  take((size_t)SCAN_NB * 4);
    uint4*  payload   = (uint4*)take((size_t)EE * 16);          // 12.8 MB
    uint4*  pk        = (uint4*)take((size_t)EE * 16);          // 12.8 MB
    int*    csr_src   = (int*)  take((size_t)EE * 4);           // 3.2 MB

    hipMemsetAsync(cnt, 0, (size_t)NN * 4, stream);

    k_node<<<(NN + 63) / 64, 256, 0, stream>>>(x, W_lin, att_src, att_dst,
                                               hbuf, a_src, a_dst);
    k_edgeA<<<(EE + 255) / 256, 256, 0, stream>>>(ei, edge_attr, W_ep, b_ep,
                                                  W_edge, att_edge, a_src, a_dst,
                                                  cnt, rank, payload);
    k_scanA<<<SCAN_NB, 256, 0, stream>>>(cnt, partial);
    k_scanB<<<1, 256, 0, stream>>>(partial, poff, row_start);
    k_scanC<<<SCAN_NB, 256, 0, stream>>>(cnt, poff, row_start);
    k_edgeB<<<(EE / 4 + 255) / 256, 256, 0, stream>>>(ei, payload, rank,
                                                      row_start, pk, csr_src);
    k_aggregate<<<(NN + 3) / 4, 256, 0, stream>>>(x, (const __half2*)hbuf,
                                                  a_src, a_dst, row_start,
                                                  (const unsigned*)pk, csr_src,
                                                  bias, ln_g, ln_b, out);
}